// Round 1
// baseline (2498.028 us; speedup 1.0000x reference)
//
#include <hip/hip_runtime.h>
#include <cfloat>
#include <math.h>

#define B_ 8
#define N_ 4096
#define D_ 64
#define S_ 1024
#define K_ 32
#define CIN_ 131  // 2*D + 3

// ---------------------------------------------------------------------------
// FPS: one block per batch. 256 threads x 16 points each. Coordinates kept in
// registers for the distance update and mirrored in LDS so thread 0 can read
// the newly selected centroid directly (no owner-broadcast step).
// 2 barriers per step. Matches pointnet2 FPS: emit current `far`, update
// dist=min(dist,d), next far = argmax (first-index tie-break, like jnp.argmax).
// ---------------------------------------------------------------------------
__global__ __launch_bounds__(256) void fps_kernel(const float* __restrict__ xyz,
                                                  int* __restrict__ fps_idx,
                                                  float* __restrict__ nxyz,
                                                  float* __restrict__ out0) {
  const int b = blockIdx.x, tid = threadIdx.x;
  __shared__ float sx[N_], sy[N_], sz[N_];
  __shared__ float s_c[3];
  __shared__ float rv[4];
  __shared__ int ri[4];
  const float* xb = xyz + (size_t)b * 3 * N_;
  float px[16], py[16], pz[16], dist[16];
#pragma unroll
  for (int i = 0; i < 16; i++) {
    int n = i * 256 + tid;
    px[i] = xb[n];
    py[i] = xb[N_ + n];
    pz[i] = xb[2 * N_ + n];
    dist[i] = 1e10f;
    sx[n] = px[i]; sy[n] = py[i]; sz[n] = pz[i];
  }
  if (tid == 0) {
    float cx = xb[0], cy = xb[N_], cz = xb[2 * N_];
    fps_idx[b * S_] = 0;
    nxyz[(size_t)(b * S_) * 3 + 0] = cx;
    nxyz[(size_t)(b * S_) * 3 + 1] = cy;
    nxyz[(size_t)(b * S_) * 3 + 2] = cz;
    out0[(size_t)b * 3 * S_ + 0] = cx;
    out0[(size_t)b * 3 * S_ + S_] = cy;
    out0[(size_t)b * 3 * S_ + 2 * S_] = cz;
    s_c[0] = cx; s_c[1] = cy; s_c[2] = cz;
  }
  __syncthreads();
  for (int s = 1; s < S_; s++) {
    const float cx = s_c[0], cy = s_c[1], cz = s_c[2];
    float best = -1.0f;
    int bi = tid;
#pragma unroll
    for (int i = 0; i < 16; i++) {
      // no-FMA arithmetic to mirror reference op order
      float dx = __fsub_rn(px[i], cx);
      float dy = __fsub_rn(py[i], cy);
      float dz = __fsub_rn(pz[i], cz);
      float d = __fadd_rn(__fadd_rn(__fmul_rn(dx, dx), __fmul_rn(dy, dy)), __fmul_rn(dz, dz));
      dist[i] = fminf(dist[i], d);
      if (dist[i] > best) { best = dist[i]; bi = i * 256 + tid; }
    }
#pragma unroll
    for (int off = 32; off >= 1; off >>= 1) {
      float ov = __shfl_xor(best, off);
      int oi = __shfl_xor(bi, off);
      if (ov > best || (ov == best && oi < bi)) { best = ov; bi = oi; }
    }
    if ((tid & 63) == 0) { rv[tid >> 6] = best; ri[tid >> 6] = bi; }
    __syncthreads();
    if (tid == 0) {
      float bv = rv[0]; int bix = ri[0];
      for (int g = 1; g < 4; g++)
        if (rv[g] > bv || (rv[g] == bv && ri[g] < bix)) { bv = rv[g]; bix = ri[g]; }
      fps_idx[b * S_ + s] = bix;
      float cx2 = sx[bix], cy2 = sy[bix], cz2 = sz[bix];
      nxyz[(size_t)(b * S_ + s) * 3 + 0] = cx2;
      nxyz[(size_t)(b * S_ + s) * 3 + 1] = cy2;
      nxyz[(size_t)(b * S_ + s) * 3 + 2] = cz2;
      out0[(size_t)b * 3 * S_ + s] = cx2;
      out0[(size_t)b * 3 * S_ + S_ + s] = cy2;
      out0[(size_t)b * 3 * S_ + 2 * S_ + s] = cz2;
      s_c[0] = cx2; s_c[1] = cy2; s_c[2] = cz2;
    }
    __syncthreads();
  }
}

// ---------------------------------------------------------------------------
// Gather anchor features: nfeat[b,s,c] = feature[b,c,fps_idx[b,s]]
// ---------------------------------------------------------------------------
__global__ __launch_bounds__(256) void gather_nf(const float* __restrict__ feature,
                                                 const int* __restrict__ fps_i,
                                                 float* __restrict__ nfeat) {
  int e = blockIdx.x * 256 + threadIdx.x;  // < B*S*D = 524288
  int b = e >> 16, rem = e & 65535;
  int s = rem >> 6, c = rem & 63;
  int n = fps_i[b * S_ + s];
  nfeat[e] = feature[((size_t)b * 64 + c) * N_ + n];
}

// ---------------------------------------------------------------------------
// kNN: one block per (b,s) query. 32 iterative block-argmins, smallest-index
// tie-break (matches lax.top_k). Distance via ||c||^2+||p||^2-2c.p (ref formula).
// ---------------------------------------------------------------------------
__global__ __launch_bounds__(256) void knn_kernel(const float* __restrict__ xyz,
                                                  const float* __restrict__ nxyz,
                                                  int* __restrict__ knn) {
  const int bs = blockIdx.x, tid = threadIdx.x;
  const int b = bs >> 10;
  const float* xb = xyz + (size_t)b * 3 * N_;
  const float cx = nxyz[(size_t)bs * 3], cy = nxyz[(size_t)bs * 3 + 1], cz = nxyz[(size_t)bs * 3 + 2];
  const float cn = __fadd_rn(__fadd_rn(__fmul_rn(cx, cx), __fmul_rn(cy, cy)), __fmul_rn(cz, cz));
  float d[16];
#pragma unroll
  for (int i = 0; i < 16; i++) {
    int n = i * 256 + tid;
    float px = xb[n], py = xb[N_ + n], pz = xb[2 * N_ + n];
    float pn = __fadd_rn(__fadd_rn(__fmul_rn(px, px), __fmul_rn(py, py)), __fmul_rn(pz, pz));
    float dot = __fadd_rn(__fadd_rn(__fmul_rn(cx, px), __fmul_rn(cy, py)), __fmul_rn(cz, pz));
    d[i] = __fsub_rn(__fadd_rn(cn, pn), __fmul_rn(2.0f, dot));
  }
  float mv = FLT_MAX; int mi = tid;
#pragma unroll
  for (int i = 0; i < 16; i++)
    if (d[i] < mv) { mv = d[i]; mi = i * 256 + tid; }
  __shared__ float rv[4];
  __shared__ int ri[4];
  __shared__ int sg;
  for (int j = 0; j < K_; j++) {
    float v = mv; int ix = mi;
#pragma unroll
    for (int off = 32; off >= 1; off >>= 1) {
      float ov = __shfl_xor(v, off);
      int oi = __shfl_xor(ix, off);
      if (ov < v || (ov == v && oi < ix)) { v = ov; ix = oi; }
    }
    if ((tid & 63) == 0) { rv[tid >> 6] = v; ri[tid >> 6] = ix; }
    __syncthreads();
    if (tid == 0) {
      float bv = rv[0]; int g = ri[0];
      for (int w = 1; w < 4; w++)
        if (rv[w] < bv || (rv[w] == bv && ri[w] < g)) { bv = rv[w]; g = ri[w]; }
      knn[(size_t)bs * K_ + j] = g;
      sg = g;
    }
    __syncthreads();
    int g = sg;
    if ((g & 255) == tid) {
      int sl = g >> 8;
#pragma unroll
      for (int i = 0; i < 16; i++)
        if (i == sl) d[i] = FLT_MAX;
      mv = FLT_MAX; mi = tid;
#pragma unroll
      for (int i = 0; i < 16; i++)
        if (d[i] < mv) { mv = d[i]; mi = i * 256 + tid; }
    }
  }
}

// ---------------------------------------------------------------------------
// Anchor-norm std: per-batch sum/sumsq partials over S*k*67 diffs.
// 64 blocks per batch (16 s-values each), f32 block partial -> f64 finalize.
// ---------------------------------------------------------------------------
__global__ __launch_bounds__(256) void std_partial(const float* __restrict__ feature,
                                                   const float* __restrict__ xyz,
                                                   const float* __restrict__ nxyz,
                                                   const float* __restrict__ nfeat,
                                                   const int* __restrict__ knn,
                                                   float* __restrict__ outp) {
  const int blk = blockIdx.x, tid = threadIdx.x;
  const int b = blk >> 6, chunk = blk & 63;
  float s = 0.f, q = 0.f;
  for (int e = tid; e < 16 * K_ * 67; e += 256) {
    int so = e / (K_ * 67);
    int rem = e - so * (K_ * 67);
    int kk = rem / 67;
    int c = rem - kk * 67;
    int bs = b * S_ + chunk * 16 + so;
    int n = knn[(size_t)bs * K_ + kk];
    float raw = (c < 64) ? feature[((size_t)b * 64 + c) * N_ + n]
                         : xyz[((size_t)b * 3 + (c - 64)) * N_ + n];
    float anc = (c < 64) ? nfeat[(size_t)bs * 64 + c]
                         : nxyz[(size_t)bs * 3 + (c - 64)];
    float dd = raw - anc;
    s += dd; q += dd * dd;
  }
#pragma unroll
  for (int off = 32; off >= 1; off >>= 1) { s += __shfl_xor(s, off); q += __shfl_xor(q, off); }
  __shared__ float rs[4], rq[4];
  if ((tid & 63) == 0) { rs[tid >> 6] = s; rq[tid >> 6] = q; }
  __syncthreads();
  if (tid == 0) {
    outp[blk * 2] = rs[0] + rs[1] + rs[2] + rs[3];
    outp[blk * 2 + 1] = rq[0] + rq[1] + rq[2] + rq[3];
  }
}

__global__ void std_final(const float* __restrict__ part, float* __restrict__ invstd) {
  int b = threadIdx.x;
  if (b < B_) {
    double s = 0.0, q = 0.0;
    for (int i = 0; i < 64; i++) {
      s += (double)part[(b * 64 + i) * 2];
      q += (double)part[(b * 64 + i) * 2 + 1];
    }
    const double n = (double)(S_ * K_ * 67);
    double var = (q - s * s / n) / (n - 1.0);  // ddof=1
    invstd[b] = (float)(1.0 / (sqrt(var) + 1e-5));
  }
}

// ---------------------------------------------------------------------------
// BN finalize: per-channel mean/biased-var over 8192 block partials (f64),
// emit fused scale/shift.
// ---------------------------------------------------------------------------
__global__ __launch_bounds__(256) void bn_finalize(const float* __restrict__ part,
                                                   const float* __restrict__ g,
                                                   const float* __restrict__ be,
                                                   float* __restrict__ bnout) {
  const int ch = blockIdx.x, tid = threadIdx.x;
  double s = 0.0, q = 0.0;
  for (int i = tid; i < B_ * S_; i += 256) {
    s += (double)part[(size_t)i * 128 + ch];
    q += (double)part[(size_t)i * 128 + 64 + ch];
  }
#pragma unroll
  for (int off = 32; off >= 1; off >>= 1) { s += __shfl_xor(s, off); q += __shfl_xor(q, off); }
  __shared__ double ls[4], lq[4];
  if ((tid & 63) == 0) { ls[tid >> 6] = s; lq[tid >> 6] = q; }
  __syncthreads();
  if (tid == 0) {
    double Ssum = ls[0] + ls[1] + ls[2] + ls[3];
    double Qsum = lq[0] + lq[1] + lq[2] + lq[3];
    const double n = (double)(B_ * S_ * K_);  // 262144
    double mu = Ssum / n;
    double var = Qsum / n - mu * mu;  // biased (jnp.var default)
    double sc = (double)g[ch] / sqrt(var + 1e-5);
    bnout[ch] = (float)sc;
    bnout[64 + ch] = (float)((double)be[ch] - mu * sc);
  }
}

// ---------------------------------------------------------------------------
// MLP: one block per (b,s) group. Recomputes gather + conv chain in 3 modes:
//   MODE 0: conv_tr -> BN-tr stat partials
//   MODE 1: conv_tr -> bn+relu -> conv1 -> BN-1 stat partials
//   MODE 2: full chain -> residual relu -> max over k -> out
// x-tile (131x32) in LDS read as broadcast float4; W transposed in LDS with
// row stride 65 (conflict-free per-lane-o reads). ub aliases xin (dead).
// ---------------------------------------------------------------------------
template <int MODE>
__global__ __launch_bounds__(256, 2) void mlp_kernel(
    const float* __restrict__ feature, const float* __restrict__ xyz,
    const float* __restrict__ nxyz, const float* __restrict__ nfeat,
    const int* __restrict__ knn, const float* __restrict__ invstd,
    const float* __restrict__ alpha, const float* __restrict__ beta,
    const float* __restrict__ w_tr, const float* __restrict__ b_tr,
    const float* __restrict__ w1, const float* __restrict__ b1,
    const float* __restrict__ w2, const float* __restrict__ b2,
    const float* __restrict__ bn_tr, const float* __restrict__ bn_1,
    float* __restrict__ bnpart, float* __restrict__ out1) {
  __shared__ __align__(16) float pool[15556];
  float* Wt = pool;                       // up to 131 rows x stride 65 = 8515 (+1 pad)
  float* xin = pool + 8516;               // 131*32 = 4192
  float* ub = xin;                        // alias (xin dead by then), 64*36
  float* tb = pool + 8516 + 4192;         // 64*36 = 2304
  float* part = pool + 8516 + 4192 + 2304;  // 512
  int* sknn = (int*)(part + 512);           // 32
  const int bs = blockIdx.x, tid = threadIdx.x;
  const int b = bs >> 10, s = bs & 1023;
  if (tid < K_) sknn[tid] = knn[(size_t)bs * K_ + tid];
  for (int e = tid; e < 64 * 131; e += 256) {
    int o = e / 131, c = e - o * 131;
    Wt[c * 65 + o] = w_tr[e];
  }
  __syncthreads();
  const float inv = invstd[b];
  for (int e = tid; e < CIN_ * K_; e += 256) {
    int c = e >> 5, kk = e & 31;
    float v;
    if (c < 67) {
      int n = sknn[kk];
      float raw = (c < 64) ? feature[((size_t)b * 64 + c) * N_ + n]
                           : xyz[((size_t)b * 3 + (c - 64)) * N_ + n];
      float anc = (c < 64) ? nfeat[(size_t)bs * 64 + c]
                           : nxyz[(size_t)bs * 3 + (c - 64)];
      v = alpha[c] * ((raw - anc) * inv) + beta[c];
    } else {
      v = nfeat[(size_t)bs * 64 + (c - 67)];
    }
    xin[e] = v;
  }
  __syncthreads();
  const int o = tid & 63, kkb = (tid >> 6) * 8;
  float acc[8];
  {
    float bv = b_tr[o];
#pragma unroll
    for (int j = 0; j < 8; j++) acc[j] = bv;
  }
  for (int c = 0; c < CIN_; c++) {
    float w = Wt[c * 65 + o];
    const float4 xa = *(const float4*)(xin + c * 32 + kkb);
    const float4 xb4 = *(const float4*)(xin + c * 32 + kkb + 4);
    acc[0] += w * xa.x; acc[1] += w * xa.y; acc[2] += w * xa.z; acc[3] += w * xa.w;
    acc[4] += w * xb4.x; acc[5] += w * xb4.y; acc[6] += w * xb4.z; acc[7] += w * xb4.w;
  }
  if (MODE == 0) {
    float s8 = 0.f, q8 = 0.f;
#pragma unroll
    for (int j = 0; j < 8; j++) { s8 += acc[j]; q8 += acc[j] * acc[j]; }
    part[(tid >> 6) * 64 + o] = s8;
    part[256 + (tid >> 6) * 64 + o] = q8;
    __syncthreads();
    if (tid < 64) {
      float ss = 0.f, qq = 0.f;
      for (int g = 0; g < 4; g++) { ss += part[g * 64 + tid]; qq += part[256 + g * 64 + tid]; }
      bnpart[(size_t)bs * 128 + tid] = ss;
      bnpart[(size_t)bs * 128 + 64 + tid] = qq;
    }
    return;
  }
  float tv[8];
  {
    float sc = bn_tr[o], sh = bn_tr[64 + o];
#pragma unroll
    for (int j = 0; j < 8; j++) {
      tv[j] = fmaxf(fmaf(sc, acc[j], sh), 0.f);
      tb[o * 36 + kkb + j] = tv[j];
    }
  }
  __syncthreads();
  for (int e = tid; e < 64 * 64; e += 256) {
    int oo = e >> 6, c = e & 63;
    Wt[c * 65 + oo] = w1[e];
  }
  __syncthreads();
  float acc2[8];
  {
    float bv = b1[o];
#pragma unroll
    for (int j = 0; j < 8; j++) acc2[j] = bv;
  }
  for (int c = 0; c < 64; c++) {
    float w = Wt[c * 65 + o];
    const float4 ta = *(const float4*)(tb + c * 36 + kkb);
    const float4 ta2 = *(const float4*)(tb + c * 36 + kkb + 4);
    acc2[0] += w * ta.x; acc2[1] += w * ta.y; acc2[2] += w * ta.z; acc2[3] += w * ta.w;
    acc2[4] += w * ta2.x; acc2[5] += w * ta2.y; acc2[6] += w * ta2.z; acc2[7] += w * ta2.w;
  }
  if (MODE == 1) {
    float s8 = 0.f, q8 = 0.f;
#pragma unroll
    for (int j = 0; j < 8; j++) { s8 += acc2[j]; q8 += acc2[j] * acc2[j]; }
    part[(tid >> 6) * 64 + o] = s8;
    part[256 + (tid >> 6) * 64 + o] = q8;
    __syncthreads();
    if (tid < 64) {
      float ss = 0.f, qq = 0.f;
      for (int g = 0; g < 4; g++) { ss += part[g * 64 + tid]; qq += part[256 + g * 64 + tid]; }
      bnpart[(size_t)bs * 128 + tid] = ss;
      bnpart[(size_t)bs * 128 + 64 + tid] = qq;
    }
    return;
  }
  {
    float sc = bn_1[o], sh = bn_1[64 + o];
#pragma unroll
    for (int j = 0; j < 8; j++) ub[o * 36 + kkb + j] = fmaxf(fmaf(sc, acc2[j], sh), 0.f);
  }
  __syncthreads();
  for (int e = tid; e < 64 * 64; e += 256) {
    int oo = e >> 6, c = e & 63;
    Wt[c * 65 + oo] = w2[e];
  }
  __syncthreads();
  float acc3[8];
  {
    float bv = b2[o];
#pragma unroll
    for (int j = 0; j < 8; j++) acc3[j] = bv;
  }
  for (int c = 0; c < 64; c++) {
    float w = Wt[c * 65 + o];
    const float4 ua = *(const float4*)(ub + c * 36 + kkb);
    const float4 ua2 = *(const float4*)(ub + c * 36 + kkb + 4);
    acc3[0] += w * ua.x; acc3[1] += w * ua.y; acc3[2] += w * ua.z; acc3[3] += w * ua.w;
    acc3[4] += w * ua2.x; acc3[5] += w * ua2.y; acc3[6] += w * ua2.z; acc3[7] += w * ua2.w;
  }
  float m = 0.f;  // relu outputs are >= 0
#pragma unroll
  for (int j = 0; j < 8; j++) m = fmaxf(m, fmaxf(acc3[j] + tv[j], 0.f));
  part[(tid >> 6) * 64 + o] = m;
  __syncthreads();
  if (tid < 64) {
    float mm = part[tid];
    for (int g = 1; g < 4; g++) mm = fmaxf(mm, part[g * 64 + tid]);
    out1[((size_t)b * 64 + tid) * S_ + s] = mm;
  }
}

// ---------------------------------------------------------------------------
extern "C" void kernel_launch(void* const* d_in, const int* in_sizes, int n_in,
                              void* d_out, int out_size, void* d_ws, size_t ws_size,
                              hipStream_t stream) {
  const float* xyz = (const float*)d_in[0];
  const float* feature = (const float*)d_in[1];
  const float* alpha = (const float*)d_in[2];
  const float* beta = (const float*)d_in[3];
  const float* w_tr = (const float*)d_in[4];
  const float* b_tr = (const float*)d_in[5];
  const float* g_tr = (const float*)d_in[6];
  const float* be_tr = (const float*)d_in[7];
  const float* w1 = (const float*)d_in[8];
  const float* b1 = (const float*)d_in[9];
  const float* g1 = (const float*)d_in[10];
  const float* be1 = (const float*)d_in[11];
  const float* w2 = (const float*)d_in[12];
  const float* b2 = (const float*)d_in[13];

  char* ws = (char*)d_ws;
  int* fps_i = (int*)(ws);                      // 32768 B
  float* nxyz = (float*)(ws + 32768);           // 98304 B
  float* nfeat = (float*)(ws + 131072);         // 2097152 B
  int* knn = (int*)(ws + 2228224);              // 1048576 B
  float* stdpart = (float*)(ws + 3276800);      // 4096 B
  float* invstd = (float*)(ws + 3280896);       // 64 B
  float* bn_tr = (float*)(ws + 3280960);        // 512 B
  float* bn_1 = (float*)(ws + 3281472);         // 512 B
  float* bnpart = (float*)(ws + 3281984);       // 4194304 B  (total ~7.5 MB)

  float* out0 = (float*)d_out;
  float* out1 = out0 + B_ * 3 * S_;

  fps_kernel<<<B_, 256, 0, stream>>>(xyz, fps_i, nxyz, out0);
  gather_nf<<<(B_ * S_ * D_) / 256, 256, 0, stream>>>(feature, fps_i, nfeat);
  knn_kernel<<<B_ * S_, 256, 0, stream>>>(xyz, nxyz, knn);
  std_partial<<<B_ * 64, 256, 0, stream>>>(feature, xyz, nxyz, nfeat, knn, stdpart);
  std_final<<<1, 64, 0, stream>>>(stdpart, invstd);
  mlp_kernel<0><<<B_ * S_, 256, 0, stream>>>(feature, xyz, nxyz, nfeat, knn, invstd,
                                             alpha, beta, w_tr, b_tr, w1, b1, w2, b2,
                                             bn_tr, bn_1, bnpart, out1);
  bn_finalize<<<64, 256, 0, stream>>>(bnpart, g_tr, be_tr, bn_tr);
  mlp_kernel<1><<<B_ * S_, 256, 0, stream>>>(feature, xyz, nxyz, nfeat, knn, invstd,
                                             alpha, beta, w_tr, b_tr, w1, b1, w2, b2,
                                             bn_tr, bn_1, bnpart, out1);
  bn_finalize<<<64, 256, 0, stream>>>(bnpart, g1, be1, bn_1);
  mlp_kernel<2><<<B_ * S_, 256, 0, stream>>>(feature, xyz, nxyz, nfeat, knn, invstd,
                                             alpha, beta, w_tr, b_tr, w1, b1, w2, b2,
                                             bn_tr, bn_1, bnpart, out1);
}

// Round 2
// 2041.246 us; speedup vs baseline: 1.2238x; 1.2238x over previous
//
#include <hip/hip_runtime.h>
#include <cfloat>
#include <math.h>

#define B_ 8
#define N_ 4096
#define D_ 64
#define S_ 1024
#define K_ 32
#define CIN_ 131  // 2*D + 3

// Monotone map: float bits -> uint32 preserving order for ALL floats.
__device__ __forceinline__ unsigned int fmono(float f) {
  unsigned int u = __float_as_uint(f);
  return u ^ ((unsigned int)((int)u >> 31) | 0x80000000u);
}

// ---------------------------------------------------------------------------
// FPS: one block per batch, 512 threads x 8 points in registers. Coordinates
// mirrored in LDS (float4). ONE barrier per step: per-wave argmax partials are
// packed into sortable u64 keys, double-buffered by step parity; every thread
// redundantly merges the 8 partials. No global memory ops inside the serial
// loop (round-1 version drained vmcnt before the 2nd barrier every step).
// ---------------------------------------------------------------------------
__global__ __launch_bounds__(512) void fps_kernel(const float* __restrict__ xyz,
                                                  int* __restrict__ fps_idx,
                                                  float* __restrict__ nxyz,
                                                  float* __restrict__ out0) {
  const int b = blockIdx.x, tid = threadIdx.x;
  __shared__ __align__(16) float4 sp[N_];              // 64 KB coord mirror
  __shared__ int si[S_];                               // selected indices
  __shared__ unsigned long long keyp[2][8];            // per-wave partials, dbuf
  const float* xb = xyz + (size_t)b * 3 * N_;
  float px[8], py[8], pz[8], dist[8];
#pragma unroll
  for (int i = 0; i < 8; i++) {
    int n = i * 512 + tid;
    px[i] = xb[n];
    py[i] = xb[N_ + n];
    pz[i] = xb[2 * N_ + n];
    dist[i] = 1e10f;
    sp[n] = make_float4(px[i], py[i], pz[i], 0.f);
  }
  if (tid == 0) si[0] = 0;
  __syncthreads();
  float cx = sp[0].x, cy = sp[0].y, cz = sp[0].z;
  const int wav = tid >> 6, lane = tid & 63;
  for (int s = 1; s < S_; s++) {
    float best = -1.0f;
    int bi = 0;
#pragma unroll
    for (int i = 0; i < 8; i++) {
      // no-FMA arithmetic, identical op order to round-1 (which validated)
      float dx = __fsub_rn(px[i], cx);
      float dy = __fsub_rn(py[i], cy);
      float dz = __fsub_rn(pz[i], cz);
      float d = __fadd_rn(__fadd_rn(__fmul_rn(dx, dx), __fmul_rn(dy, dy)), __fmul_rn(dz, dz));
      dist[i] = fminf(dist[i], d);
      if (dist[i] > best) { best = dist[i]; bi = i * 512 + tid; }
    }
    // pack (value, index): maximize value, then minimize index
    unsigned long long key =
        ((unsigned long long)fmono(best) << 32) | (unsigned int)(4095 - bi);
#pragma unroll
    for (int off = 32; off >= 1; off >>= 1) {
      unsigned long long ok = __shfl_xor(key, off);
      if (ok > key) key = ok;
    }
    if (lane == 0) keyp[s & 1][wav] = key;
    __syncthreads();
    unsigned long long kmax = keyp[s & 1][0];
#pragma unroll
    for (int w = 1; w < 8; w++) {
      unsigned long long k2 = keyp[s & 1][w];
      if (k2 > kmax) kmax = k2;
    }
    int bix = 4095 - (int)(kmax & 0xffffffffull);
    if (tid == 0) si[s] = bix;
    float4 c = sp[bix];
    cx = c.x; cy = c.y; cz = c.z;
  }
  __syncthreads();
  // flush all global outputs coalesced, outside the serial loop
  for (int e = tid; e < S_; e += 512) {
    int n = si[e];
    fps_idx[b * S_ + e] = n;
    float4 c = sp[n];
    nxyz[(size_t)(b * S_ + e) * 3 + 0] = c.x;
    nxyz[(size_t)(b * S_ + e) * 3 + 1] = c.y;
    nxyz[(size_t)(b * S_ + e) * 3 + 2] = c.z;
    out0[(size_t)b * 3 * S_ + e] = c.x;
    out0[(size_t)b * 3 * S_ + S_ + e] = c.y;
    out0[(size_t)b * 3 * S_ + 2 * S_ + e] = c.z;
  }
}

// ---------------------------------------------------------------------------
// Gather anchor features: nfeat[b,s,c] = feature[b,c,fps_idx[b,s]]
// ---------------------------------------------------------------------------
__global__ __launch_bounds__(256) void gather_nf(const float* __restrict__ feature,
                                                 const int* __restrict__ fps_i,
                                                 float* __restrict__ nfeat) {
  int e = blockIdx.x * 256 + threadIdx.x;  // < B*S*D = 524288
  int b = e >> 16, rem = e & 65535;
  int s = rem >> 6, c = rem & 63;
  int n = fps_i[b * S_ + s];
  nfeat[e] = feature[((size_t)b * 64 + c) * N_ + n];
}

// ---------------------------------------------------------------------------
// kNN: one block per (b,s) query. 32 iterative block-argmins with packed-u64
// keys (min dist, then min index = lax.top_k tie-break). One barrier per
// round (double-buffered partials), indices flushed from LDS after the loop.
// ---------------------------------------------------------------------------
__global__ __launch_bounds__(256) void knn_kernel(const float* __restrict__ xyz,
                                                  const float* __restrict__ nxyz,
                                                  int* __restrict__ knn) {
  const int bs = blockIdx.x, tid = threadIdx.x;
  const int b = bs >> 10;
  const float* xb = xyz + (size_t)b * 3 * N_;
  const float cx = nxyz[(size_t)bs * 3], cy = nxyz[(size_t)bs * 3 + 1], cz = nxyz[(size_t)bs * 3 + 2];
  const float cn = __fadd_rn(__fadd_rn(__fmul_rn(cx, cx), __fmul_rn(cy, cy)), __fmul_rn(cz, cz));
  float d[16];
#pragma unroll
  for (int i = 0; i < 16; i++) {
    int n = i * 256 + tid;
    float px = xb[n], py = xb[N_ + n], pz = xb[2 * N_ + n];
    float pn = __fadd_rn(__fadd_rn(__fmul_rn(px, px), __fmul_rn(py, py)), __fmul_rn(pz, pz));
    float dot = __fadd_rn(__fadd_rn(__fmul_rn(cx, px), __fmul_rn(cy, py)), __fmul_rn(cz, pz));
    d[i] = __fsub_rn(__fadd_rn(cn, pn), __fmul_rn(2.0f, dot));
  }
  float mv = FLT_MAX;
  int mi = tid;
#pragma unroll
  for (int i = 0; i < 16; i++)
    if (d[i] < mv) { mv = d[i]; mi = i * 256 + tid; }
  __shared__ unsigned long long keyp[2][4];
  __shared__ int skk[K_];
  const int wav = tid >> 6, lane = tid & 63;
  for (int j = 0; j < K_; j++) {
    unsigned long long key = ((unsigned long long)fmono(mv) << 32) | (unsigned int)mi;
#pragma unroll
    for (int off = 32; off >= 1; off >>= 1) {
      unsigned long long ok = __shfl_xor(key, off);
      if (ok < key) key = ok;
    }
    if (lane == 0) keyp[j & 1][wav] = key;
    __syncthreads();
    unsigned long long kmin = keyp[j & 1][0];
#pragma unroll
    for (int w = 1; w < 4; w++) {
      unsigned long long k2 = keyp[j & 1][w];
      if (k2 < kmin) kmin = k2;
    }
    int g = (int)(kmin & 0xffffffffull);
    if (tid == 0) skk[j] = g;
    if ((g & 255) == tid) {
      int sl = g >> 8;
#pragma unroll
      for (int i = 0; i < 16; i++)
        if (i == sl) d[i] = FLT_MAX;
      mv = FLT_MAX; mi = tid;
#pragma unroll
      for (int i = 0; i < 16; i++)
        if (d[i] < mv) { mv = d[i]; mi = i * 256 + tid; }
    }
  }
  __syncthreads();
  if (tid < K_) knn[(size_t)bs * K_ + tid] = skk[tid];
}

// ---------------------------------------------------------------------------
// Anchor-norm std: per-batch sum/sumsq partials over S*k*67 diffs.
// ---------------------------------------------------------------------------
__global__ __launch_bounds__(256) void std_partial(const float* __restrict__ feature,
                                                   const float* __restrict__ xyz,
                                                   const float* __restrict__ nxyz,
                                                   const float* __restrict__ nfeat,
                                                   const int* __restrict__ knn,
                                                   float* __restrict__ outp) {
  const int blk = blockIdx.x, tid = threadIdx.x;
  const int b = blk >> 6, chunk = blk & 63;
  float s = 0.f, q = 0.f;
  for (int e = tid; e < 16 * K_ * 67; e += 256) {
    int so = e / (K_ * 67);
    int rem = e - so * (K_ * 67);
    int kk = rem / 67;
    int c = rem - kk * 67;
    int bs = b * S_ + chunk * 16 + so;
    int n = knn[(size_t)bs * K_ + kk];
    float raw = (c < 64) ? feature[((size_t)b * 64 + c) * N_ + n]
                         : xyz[((size_t)b * 3 + (c - 64)) * N_ + n];
    float anc = (c < 64) ? nfeat[(size_t)bs * 64 + c]
                         : nxyz[(size_t)bs * 3 + (c - 64)];
    float dd = raw - anc;
    s += dd; q += dd * dd;
  }
#pragma unroll
  for (int off = 32; off >= 1; off >>= 1) { s += __shfl_xor(s, off); q += __shfl_xor(q, off); }
  __shared__ float rs[4], rq[4];
  if ((tid & 63) == 0) { rs[tid >> 6] = s; rq[tid >> 6] = q; }
  __syncthreads();
  if (tid == 0) {
    outp[blk * 2] = rs[0] + rs[1] + rs[2] + rs[3];
    outp[blk * 2 + 1] = rq[0] + rq[1] + rq[2] + rq[3];
  }
}

__global__ void std_final(const float* __restrict__ part, float* __restrict__ invstd) {
  int b = threadIdx.x;
  if (b < B_) {
    double s = 0.0, q = 0.0;
    for (int i = 0; i < 64; i++) {
      s += (double)part[(b * 64 + i) * 2];
      q += (double)part[(b * 64 + i) * 2 + 1];
    }
    const double n = (double)(S_ * K_ * 67);
    double var = (q - s * s / n) / (n - 1.0);  // ddof=1
    invstd[b] = (float)(1.0 / (sqrt(var) + 1e-5));
  }
}

// ---------------------------------------------------------------------------
// BN finalize: per-channel mean/biased-var over 8192 block partials (f64),
// emit fused scale/shift.
// ---------------------------------------------------------------------------
__global__ __launch_bounds__(256) void bn_finalize(const float* __restrict__ part,
                                                   const float* __restrict__ g,
                                                   const float* __restrict__ be,
                                                   float* __restrict__ bnout) {
  const int ch = blockIdx.x, tid = threadIdx.x;
  double s = 0.0, q = 0.0;
  for (int i = tid; i < B_ * S_; i += 256) {
    s += (double)part[(size_t)i * 128 + ch];
    q += (double)part[(size_t)i * 128 + 64 + ch];
  }
#pragma unroll
  for (int off = 32; off >= 1; off >>= 1) { s += __shfl_xor(s, off); q += __shfl_xor(q, off); }
  __shared__ double ls[4], lq[4];
  if ((tid & 63) == 0) { ls[tid >> 6] = s; lq[tid >> 6] = q; }
  __syncthreads();
  if (tid == 0) {
    double Ssum = ls[0] + ls[1] + ls[2] + ls[3];
    double Qsum = lq[0] + lq[1] + lq[2] + lq[3];
    const double n = (double)(B_ * S_ * K_);  // 262144
    double mu = Ssum / n;
    double var = Qsum / n - mu * mu;  // biased (jnp.var default)
    double sc = (double)g[ch] / sqrt(var + 1e-5);
    bnout[ch] = (float)sc;
    bnout[64 + ch] = (float)((double)be[ch] - mu * sc);
  }
}

// ---------------------------------------------------------------------------
// MLP: one block per (b,s) group. Recomputes gather + conv chain in 3 modes:
//   MODE 0: conv_tr -> BN-tr stat partials
//   MODE 1: conv_tr -> bn+relu -> conv1 -> BN-1 stat partials
//   MODE 2: full chain -> residual relu -> max over k -> out
// ---------------------------------------------------------------------------
template <int MODE>
__global__ __launch_bounds__(256, 2) void mlp_kernel(
    const float* __restrict__ feature, const float* __restrict__ xyz,
    const float* __restrict__ nxyz, const float* __restrict__ nfeat,
    const int* __restrict__ knn, const float* __restrict__ invstd,
    const float* __restrict__ alpha, const float* __restrict__ beta,
    const float* __restrict__ w_tr, const float* __restrict__ b_tr,
    const float* __restrict__ w1, const float* __restrict__ b1,
    const float* __restrict__ w2, const float* __restrict__ b2,
    const float* __restrict__ bn_tr, const float* __restrict__ bn_1,
    float* __restrict__ bnpart, float* __restrict__ out1) {
  __shared__ __align__(16) float pool[15556];
  float* Wt = pool;                       // up to 131 rows x stride 65
  float* xin = pool + 8516;               // 131*32 = 4192
  float* ub = xin;                        // alias (xin dead by then)
  float* tb = pool + 8516 + 4192;         // 64*36 = 2304
  float* part = pool + 8516 + 4192 + 2304;  // 512
  int* sknn = (int*)(part + 512);           // 32
  const int bs = blockIdx.x, tid = threadIdx.x;
  const int b = bs >> 10, s = bs & 1023;
  if (tid < K_) sknn[tid] = knn[(size_t)bs * K_ + tid];
  for (int e = tid; e < 64 * 131; e += 256) {
    int o = e / 131, c = e - o * 131;
    Wt[c * 65 + o] = w_tr[e];
  }
  __syncthreads();
  const float inv = invstd[b];
  for (int e = tid; e < CIN_ * K_; e += 256) {
    int c = e >> 5, kk = e & 31;
    float v;
    if (c < 67) {
      int n = sknn[kk];
      float raw = (c < 64) ? feature[((size_t)b * 64 + c) * N_ + n]
                           : xyz[((size_t)b * 3 + (c - 64)) * N_ + n];
      float anc = (c < 64) ? nfeat[(size_t)bs * 64 + c]
                           : nxyz[(size_t)bs * 3 + (c - 64)];
      v = alpha[c] * ((raw - anc) * inv) + beta[c];
    } else {
      v = nfeat[(size_t)bs * 64 + (c - 67)];
    }
    xin[e] = v;
  }
  __syncthreads();
  const int o = tid & 63, kkb = (tid >> 6) * 8;
  float acc[8];
  {
    float bv = b_tr[o];
#pragma unroll
    for (int j = 0; j < 8; j++) acc[j] = bv;
  }
  for (int c = 0; c < CIN_; c++) {
    float w = Wt[c * 65 + o];
    const float4 xa = *(const float4*)(xin + c * 32 + kkb);
    const float4 xb4 = *(const float4*)(xin + c * 32 + kkb + 4);
    acc[0] += w * xa.x; acc[1] += w * xa.y; acc[2] += w * xa.z; acc[3] += w * xa.w;
    acc[4] += w * xb4.x; acc[5] += w * xb4.y; acc[6] += w * xb4.z; acc[7] += w * xb4.w;
  }
  if (MODE == 0) {
    float s8 = 0.f, q8 = 0.f;
#pragma unroll
    for (int j = 0; j < 8; j++) { s8 += acc[j]; q8 += acc[j] * acc[j]; }
    part[(tid >> 6) * 64 + o] = s8;
    part[256 + (tid >> 6) * 64 + o] = q8;
    __syncthreads();
    if (tid < 64) {
      float ss = 0.f, qq = 0.f;
      for (int g = 0; g < 4; g++) { ss += part[g * 64 + tid]; qq += part[256 + g * 64 + tid]; }
      bnpart[(size_t)bs * 128 + tid] = ss;
      bnpart[(size_t)bs * 128 + 64 + tid] = qq;
    }
    return;
  }
  float tv[8];
  {
    float sc = bn_tr[o], sh = bn_tr[64 + o];
#pragma unroll
    for (int j = 0; j < 8; j++) {
      tv[j] = fmaxf(fmaf(sc, acc[j], sh), 0.f);
      tb[o * 36 + kkb + j] = tv[j];
    }
  }
  __syncthreads();
  for (int e = tid; e < 64 * 64; e += 256) {
    int oo = e >> 6, c = e & 63;
    Wt[c * 65 + oo] = w1[e];
  }
  __syncthreads();
  float acc2[8];
  {
    float bv = b1[o];
#pragma unroll
    for (int j = 0; j < 8; j++) acc2[j] = bv;
  }
  for (int c = 0; c < 64; c++) {
    float w = Wt[c * 65 + o];
    const float4 ta = *(const float4*)(tb + c * 36 + kkb);
    const float4 ta2 = *(const float4*)(tb + c * 36 + kkb + 4);
    acc2[0] += w * ta.x; acc2[1] += w * ta.y; acc2[2] += w * ta.z; acc2[3] += w * ta.w;
    acc2[4] += w * ta2.x; acc2[5] += w * ta2.y; acc2[6] += w * ta2.z; acc2[7] += w * ta2.w;
  }
  if (MODE == 1) {
    float s8 = 0.f, q8 = 0.f;
#pragma unroll
    for (int j = 0; j < 8; j++) { s8 += acc2[j]; q8 += acc2[j] * acc2[j]; }
    part[(tid >> 6) * 64 + o] = s8;
    part[256 + (tid >> 6) * 64 + o] = q8;
    __syncthreads();
    if (tid < 64) {
      float ss = 0.f, qq = 0.f;
      for (int g = 0; g < 4; g++) { ss += part[g * 64 + tid]; qq += part[256 + g * 64 + tid]; }
      bnpart[(size_t)bs * 128 + tid] = ss;
      bnpart[(size_t)bs * 128 + 64 + tid] = qq;
    }
    return;
  }
  {
    float sc = bn_1[o], sh = bn_1[64 + o];
#pragma unroll
    for (int j = 0; j < 8; j++) ub[o * 36 + kkb + j] = fmaxf(fmaf(sc, acc2[j], sh), 0.f);
  }
  __syncthreads();
  for (int e = tid; e < 64 * 64; e += 256) {
    int oo = e >> 6, c = e & 63;
    Wt[c * 65 + oo] = w2[e];
  }
  __syncthreads();
  float acc3[8];
  {
    float bv = b2[o];
#pragma unroll
    for (int j = 0; j < 8; j++) acc3[j] = bv;
  }
  for (int c = 0; c < 64; c++) {
    float w = Wt[c * 65 + o];
    const float4 ua = *(const float4*)(ub + c * 36 + kkb);
    const float4 ua2 = *(const float4*)(ub + c * 36 + kkb + 4);
    acc3[0] += w * ua.x; acc3[1] += w * ua.y; acc3[2] += w * ua.z; acc3[3] += w * ua.w;
    acc3[4] += w * ua2.x; acc3[5] += w * ua2.y; acc3[6] += w * ua2.z; acc3[7] += w * ua2.w;
  }
  float m = 0.f;  // relu outputs are >= 0
#pragma unroll
  for (int j = 0; j < 8; j++) m = fmaxf(m, fmaxf(acc3[j] + tv[j], 0.f));
  part[(tid >> 6) * 64 + o] = m;
  __syncthreads();
  if (tid < 64) {
    float mm = part[tid];
    for (int g = 1; g < 4; g++) mm = fmaxf(mm, part[g * 64 + tid]);
    out1[((size_t)b * 64 + tid) * S_ + s] = mm;
  }
}

// ---------------------------------------------------------------------------
extern "C" void kernel_launch(void* const* d_in, const int* in_sizes, int n_in,
                              void* d_out, int out_size, void* d_ws, size_t ws_size,
                              hipStream_t stream) {
  const float* xyz = (const float*)d_in[0];
  const float* feature = (const float*)d_in[1];
  const float* alpha = (const float*)d_in[2];
  const float* beta = (const float*)d_in[3];
  const float* w_tr = (const float*)d_in[4];
  const float* b_tr = (const float*)d_in[5];
  const float* g_tr = (const float*)d_in[6];
  const float* be_tr = (const float*)d_in[7];
  const float* w1 = (const float*)d_in[8];
  const float* b1 = (const float*)d_in[9];
  const float* g1 = (const float*)d_in[10];
  const float* be1 = (const float*)d_in[11];
  const float* w2 = (const float*)d_in[12];
  const float* b2 = (const float*)d_in[13];

  char* ws = (char*)d_ws;
  int* fps_i = (int*)(ws);                      // 32768 B
  float* nxyz = (float*)(ws + 32768);           // 98304 B
  float* nfeat = (float*)(ws + 131072);         // 2097152 B
  int* knn = (int*)(ws + 2228224);              // 1048576 B
  float* stdpart = (float*)(ws + 3276800);      // 4096 B
  float* invstd = (float*)(ws + 3280896);       // 64 B
  float* bn_tr = (float*)(ws + 3280960);        // 512 B
  float* bn_1 = (float*)(ws + 3281472);         // 512 B
  float* bnpart = (float*)(ws + 3281984);       // 4194304 B

  float* out0 = (float*)d_out;
  float* out1 = out0 + B_ * 3 * S_;

  fps_kernel<<<B_, 512, 0, stream>>>(xyz, fps_i, nxyz, out0);
  gather_nf<<<(B_ * S_ * D_) / 256, 256, 0, stream>>>(feature, fps_i, nfeat);
  knn_kernel<<<B_ * S_, 256, 0, stream>>>(xyz, nxyz, knn);
  std_partial<<<B_ * 64, 256, 0, stream>>>(feature, xyz, nxyz, nfeat, knn, stdpart);
  std_final<<<1, 64, 0, stream>>>(stdpart, invstd);
  mlp_kernel<0><<<B_ * S_, 256, 0, stream>>>(feature, xyz, nxyz, nfeat, knn, invstd,
                                             alpha, beta, w_tr, b_tr, w1, b1, w2, b2,
                                             bn_tr, bn_1, bnpart, out1);
  bn_finalize<<<64, 256, 0, stream>>>(bnpart, g_tr, be_tr, bn_tr);
  mlp_kernel<1><<<B_ * S_, 256, 0, stream>>>(feature, xyz, nxyz, nfeat, knn, invstd,
                                             alpha, beta, w_tr, b_tr, w1, b1, w2, b2,
                                             bn_tr, bn_1, bnpart, out1);
  bn_finalize<<<64, 256, 0, stream>>>(bnpart, g1, be1, bn_1);
  mlp_kernel<2><<<B_ * S_, 256, 0, stream>>>(feature, xyz, nxyz, nfeat, knn, invstd,
                                             alpha, beta, w_tr, b_tr, w1, b1, w2, b2,
                                             bn_tr, bn_1, bnpart, out1);
}

// Round 4
// 1865.136 us; speedup vs baseline: 1.3393x; 1.0944x over previous
//
#include <hip/hip_runtime.h>
#include <cfloat>
#include <math.h>

#define B_ 8
#define N_ 4096
#define D_ 64
#define S_ 1024
#define K_ 32
#define CIN_ 131  // 2*D + 3

// Wave(64)-wide float max via DPP (VALU pipe, no DS ops). Valid for finite
// non-negative floats (squared distances). Result broadcast via readlane 63.
__device__ __forceinline__ float wave_max_f32_dpp(float v) {
  int x = __float_as_int(v);
#define STEP(ctrl)                                                        \
  {                                                                       \
    int t = __builtin_amdgcn_update_dpp(x, x, ctrl, 0xf, 0xf, false);     \
    v = fmaxf(v, __int_as_float(t));                                      \
    x = __float_as_int(v);                                                \
  }
  STEP(0x111)  // row_shr:1
  STEP(0x112)  // row_shr:2
  STEP(0x114)  // row_shr:4
  STEP(0x118)  // row_shr:8  -> lane 15/31/47/63 hold row maxima
  STEP(0x142)  // row_bcast15 -> lane 31 = max(0..31), lane 63 = max(32..63)
  STEP(0x143)  // row_bcast31 -> lane 63 = max(all)
#undef STEP
  return __int_as_float(__builtin_amdgcn_readlane(x, 63));
}

// ---------------------------------------------------------------------------
// FPS: one block per batch, 512 threads. Thread t owns CONTIGUOUS points
// [8t, 8t+8) so lane order == index order (tie-break = smallest index, like
// jnp.argmax). Per step: local argmax (registers) -> wave max via DPP (VALU)
// -> ballot+readlane index resolve -> packed u64 per-wave winner in LDS
// (double-buffered) -> ONE barrier -> all threads tree-merge 8 keys -> read
// next centroid from LDS float4 mirror. No global ops in the loop.
// NOTE float4 offsets: y row = element N_ -> slot N_/4=1024, z -> 2048.
// (Round-3 bug: used 2048/4096 = element offsets, read z as y and OOB as z.)
// ---------------------------------------------------------------------------
__global__ __launch_bounds__(512) void fps_kernel(const float* __restrict__ xyz,
                                                  int* __restrict__ fps_idx,
                                                  float* __restrict__ nxyz,
                                                  float* __restrict__ out0) {
  const int b = blockIdx.x, tid = threadIdx.x;
  __shared__ __align__(16) float4 sp[N_];    // 64 KB coord mirror
  __shared__ int si[S_];                     // selected indices
  __shared__ unsigned long long keyp[2][8];  // per-wave winners, dbuf
  const float* xb = xyz + (size_t)b * 3 * N_;
  const float4* xv = (const float4*)xb;
  float px[8], py[8], pz[8], dist[8];
  {
    float4 x0 = xv[2 * tid], x1 = xv[2 * tid + 1];
    float4 y0 = xv[1024 + 2 * tid], y1 = xv[1024 + 2 * tid + 1];
    float4 z0 = xv[2048 + 2 * tid], z1 = xv[2048 + 2 * tid + 1];
    px[0] = x0.x; px[1] = x0.y; px[2] = x0.z; px[3] = x0.w;
    px[4] = x1.x; px[5] = x1.y; px[6] = x1.z; px[7] = x1.w;
    py[0] = y0.x; py[1] = y0.y; py[2] = y0.z; py[3] = y0.w;
    py[4] = y1.x; py[5] = y1.y; py[6] = y1.z; py[7] = y1.w;
    pz[0] = z0.x; pz[1] = z0.y; pz[2] = z0.z; pz[3] = z0.w;
    pz[4] = z1.x; pz[5] = z1.y; pz[6] = z1.z; pz[7] = z1.w;
#pragma unroll
    for (int i = 0; i < 8; i++) {
      dist[i] = 1e10f;
      sp[8 * tid + i] = make_float4(px[i], py[i], pz[i], 0.f);
    }
  }
  if (tid == 0) si[0] = 0;
  __syncthreads();
  float cx = sp[0].x, cy = sp[0].y, cz = sp[0].z;
  const int wav = tid >> 6;
  for (int s = 1; s < S_; s++) {
    float best = -1.0f;
    int bi = 8 * tid;
#pragma unroll
    for (int i = 0; i < 8; i++) {
      // no-FMA arithmetic, identical op order to validated rounds
      float dx = __fsub_rn(px[i], cx);
      float dy = __fsub_rn(py[i], cy);
      float dz = __fsub_rn(pz[i], cz);
      float d = __fadd_rn(__fadd_rn(__fmul_rn(dx, dx), __fmul_rn(dy, dy)), __fmul_rn(dz, dz));
      dist[i] = fminf(dist[i], d);
      if (dist[i] > best) { best = dist[i]; bi = 8 * tid + i; }  // strict >: first (=smallest) idx
    }
    // wave argmax: DPP value max, then lowest matching lane = smallest index
    float wmax = wave_max_f32_dpp(best);
    unsigned long long m = __ballot(best == wmax);
    int l = __ffsll(m) - 1;
    int widx = __builtin_amdgcn_readlane(bi, l);
    if ((tid & 63) == 0)
      keyp[s & 1][wav] =
          ((unsigned long long)(unsigned int)__float_as_int(wmax) << 32) |
          (unsigned int)(4095 - widx);
    __syncthreads();
    // tree-merge 8 per-wave winners (max val, tie -> min index)
    unsigned long long k0 = keyp[s & 1][0], k1 = keyp[s & 1][1];
    unsigned long long k2 = keyp[s & 1][2], k3 = keyp[s & 1][3];
    unsigned long long k4 = keyp[s & 1][4], k5 = keyp[s & 1][5];
    unsigned long long k6 = keyp[s & 1][6], k7 = keyp[s & 1][7];
    unsigned long long a0 = k0 > k1 ? k0 : k1, a1 = k2 > k3 ? k2 : k3;
    unsigned long long a2 = k4 > k5 ? k4 : k5, a3 = k6 > k7 ? k6 : k7;
    unsigned long long b0 = a0 > a1 ? a0 : a1, b1 = a2 > a3 ? a2 : a3;
    unsigned long long kmax = b0 > b1 ? b0 : b1;
    int bix = 4095 - (int)(kmax & 0xfffull);
    if (tid == 0) si[s] = bix;
    float4 c = sp[bix];
    cx = c.x; cy = c.y; cz = c.z;
  }
  __syncthreads();
  // flush all global outputs coalesced, outside the serial loop
  for (int e = tid; e < S_; e += 512) {
    int n = si[e];
    fps_idx[b * S_ + e] = n;
    float4 c = sp[n];
    nxyz[(size_t)(b * S_ + e) * 3 + 0] = c.x;
    nxyz[(size_t)(b * S_ + e) * 3 + 1] = c.y;
    nxyz[(size_t)(b * S_ + e) * 3 + 2] = c.z;
    out0[(size_t)b * 3 * S_ + e] = c.x;
    out0[(size_t)b * 3 * S_ + S_ + e] = c.y;
    out0[(size_t)b * 3 * S_ + 2 * S_ + e] = c.z;
  }
}

// ---------------------------------------------------------------------------
// Gather anchor features: nfeat[b,s,c] = feature[b,c,fps_idx[b,s]]
// ---------------------------------------------------------------------------
__global__ __launch_bounds__(256) void gather_nf(const float* __restrict__ feature,
                                                 const int* __restrict__ fps_i,
                                                 float* __restrict__ nfeat) {
  int e = blockIdx.x * 256 + threadIdx.x;  // < B*S*D = 524288
  int b = e >> 16, rem = e & 65535;
  int s = rem >> 6, c = rem & 63;
  int n = fps_i[b * S_ + s];
  nfeat[e] = feature[((size_t)b * 64 + c) * N_ + n];
}

// ---------------------------------------------------------------------------
// kNN: one block per (b,s) query. 32 iterative block-argmins with packed-u64
// keys (min dist, then min index = lax.top_k tie-break). One barrier per
// round (double-buffered partials), indices flushed from LDS after the loop.
// ---------------------------------------------------------------------------
__global__ __launch_bounds__(256) void knn_kernel(const float* __restrict__ xyz,
                                                  const float* __restrict__ nxyz,
                                                  int* __restrict__ knn) {
  const int bs = blockIdx.x, tid = threadIdx.x;
  const int b = bs >> 10;
  const float* xb = xyz + (size_t)b * 3 * N_;
  const float cx = nxyz[(size_t)bs * 3], cy = nxyz[(size_t)bs * 3 + 1], cz = nxyz[(size_t)bs * 3 + 2];
  const float cn = __fadd_rn(__fadd_rn(__fmul_rn(cx, cx), __fmul_rn(cy, cy)), __fmul_rn(cz, cz));
  float d[16];
#pragma unroll
  for (int i = 0; i < 16; i++) {
    int n = i * 256 + tid;
    float px = xb[n], py = xb[N_ + n], pz = xb[2 * N_ + n];
    float pn = __fadd_rn(__fadd_rn(__fmul_rn(px, px), __fmul_rn(py, py)), __fmul_rn(pz, pz));
    float dot = __fadd_rn(__fadd_rn(__fmul_rn(cx, px), __fmul_rn(cy, py)), __fmul_rn(cz, pz));
    d[i] = __fsub_rn(__fadd_rn(cn, pn), __fmul_rn(2.0f, dot));
  }
  float mv = FLT_MAX;
  int mi = tid;
#pragma unroll
  for (int i = 0; i < 16; i++)
    if (d[i] < mv) { mv = d[i]; mi = i * 256 + tid; }
  __shared__ unsigned long long keyp[2][4];
  __shared__ int skk[K_];
  const int wav = tid >> 6, lane = tid & 63;
  for (int j = 0; j < K_; j++) {
    unsigned int u = __float_as_uint(mv);
    u ^= ((unsigned int)((int)u >> 31) | 0x80000000u);  // monotone map
    unsigned long long key = ((unsigned long long)u << 32) | (unsigned int)mi;
#pragma unroll
    for (int off = 32; off >= 1; off >>= 1) {
      unsigned long long ok = __shfl_xor(key, off);
      if (ok < key) key = ok;
    }
    if (lane == 0) keyp[j & 1][wav] = key;
    __syncthreads();
    unsigned long long kmin = keyp[j & 1][0];
#pragma unroll
    for (int w = 1; w < 4; w++) {
      unsigned long long k2 = keyp[j & 1][w];
      if (k2 < kmin) kmin = k2;
    }
    int g = (int)(kmin & 0xffffffffull);
    if (tid == 0) skk[j] = g;
    if ((g & 255) == tid) {
      int sl = g >> 8;
#pragma unroll
      for (int i = 0; i < 16; i++)
        if (i == sl) d[i] = FLT_MAX;
      mv = FLT_MAX; mi = tid;
#pragma unroll
      for (int i = 0; i < 16; i++)
        if (d[i] < mv) { mv = d[i]; mi = i * 256 + tid; }
    }
  }
  __syncthreads();
  if (tid < K_) knn[(size_t)bs * K_ + tid] = skk[tid];
}

// ---------------------------------------------------------------------------
// Anchor-norm std: per-batch sum/sumsq partials over S*k*67 diffs.
// ---------------------------------------------------------------------------
__global__ __launch_bounds__(256) void std_partial(const float* __restrict__ feature,
                                                   const float* __restrict__ xyz,
                                                   const float* __restrict__ nxyz,
                                                   const float* __restrict__ nfeat,
                                                   const int* __restrict__ knn,
                                                   float* __restrict__ outp) {
  const int blk = blockIdx.x, tid = threadIdx.x;
  const int b = blk >> 6, chunk = blk & 63;
  float s = 0.f, q = 0.f;
  for (int e = tid; e < 16 * K_ * 67; e += 256) {
    int so = e / (K_ * 67);
    int rem = e - so * (K_ * 67);
    int kk = rem / 67;
    int c = rem - kk * 67;
    int bs = b * S_ + chunk * 16 + so;
    int n = knn[(size_t)bs * K_ + kk];
    float raw = (c < 64) ? feature[((size_t)b * 64 + c) * N_ + n]
                         : xyz[((size_t)b * 3 + (c - 64)) * N_ + n];
    float anc = (c < 64) ? nfeat[(size_t)bs * 64 + c]
                         : nxyz[(size_t)bs * 3 + (c - 64)];
    float dd = raw - anc;
    s += dd; q += dd * dd;
  }
#pragma unroll
  for (int off = 32; off >= 1; off >>= 1) { s += __shfl_xor(s, off); q += __shfl_xor(q, off); }
  __shared__ float rs[4], rq[4];
  if ((tid & 63) == 0) { rs[tid >> 6] = s; rq[tid >> 6] = q; }
  __syncthreads();
  if (tid == 0) {
    outp[blk * 2] = rs[0] + rs[1] + rs[2] + rs[3];
    outp[blk * 2 + 1] = rq[0] + rq[1] + rq[2] + rq[3];
  }
}

__global__ void std_final(const float* __restrict__ part, float* __restrict__ invstd) {
  int b = threadIdx.x;
  if (b < B_) {
    double s = 0.0, q = 0.0;
    for (int i = 0; i < 64; i++) {
      s += (double)part[(b * 64 + i) * 2];
      q += (double)part[(b * 64 + i) * 2 + 1];
    }
    const double n = (double)(S_ * K_ * 67);
    double var = (q - s * s / n) / (n - 1.0);  // ddof=1
    invstd[b] = (float)(1.0 / (sqrt(var) + 1e-5));
  }
}

// ---------------------------------------------------------------------------
// BN finalize: per-channel mean/biased-var over 8192 block partials (f64),
// emit fused scale/shift.
// ---------------------------------------------------------------------------
__global__ __launch_bounds__(256) void bn_finalize(const float* __restrict__ part,
                                                   const float* __restrict__ g,
                                                   const float* __restrict__ be,
                                                   float* __restrict__ bnout) {
  const int ch = blockIdx.x, tid = threadIdx.x;
  double s = 0.0, q = 0.0;
  for (int i = tid; i < B_ * S_; i += 256) {
    s += (double)part[(size_t)i * 128 + ch];
    q += (double)part[(size_t)i * 128 + 64 + ch];
  }
#pragma unroll
  for (int off = 32; off >= 1; off >>= 1) { s += __shfl_xor(s, off); q += __shfl_xor(q, off); }
  __shared__ double ls[4], lq[4];
  if ((tid & 63) == 0) { ls[tid >> 6] = s; lq[tid >> 6] = q; }
  __syncthreads();
  if (tid == 0) {
    double Ssum = ls[0] + ls[1] + ls[2] + ls[3];
    double Qsum = lq[0] + lq[1] + lq[2] + lq[3];
    const double n = (double)(B_ * S_ * K_);  // 262144
    double mu = Ssum / n;
    double var = Qsum / n - mu * mu;  // biased (jnp.var default)
    double sc = (double)g[ch] / sqrt(var + 1e-5);
    bnout[ch] = (float)sc;
    bnout[64 + ch] = (float)((double)be[ch] - mu * sc);
  }
}

// ---------------------------------------------------------------------------
// MLP: one block per (b,s) group. Recomputes gather + conv chain in 3 modes:
//   MODE 0: conv_tr -> BN-tr stat partials
//   MODE 1: conv_tr -> bn+relu -> conv1 -> BN-1 stat partials
//   MODE 2: full chain -> residual relu -> max over k -> out
// ---------------------------------------------------------------------------
template <int MODE>
__global__ __launch_bounds__(256, 2) void mlp_kernel(
    const float* __restrict__ feature, const float* __restrict__ xyz,
    const float* __restrict__ nxyz, const float* __restrict__ nfeat,
    const int* __restrict__ knn, const float* __restrict__ invstd,
    const float* __restrict__ alpha, const float* __restrict__ beta,
    const float* __restrict__ w_tr, const float* __restrict__ b_tr,
    const float* __restrict__ w1, const float* __restrict__ b1,
    const float* __restrict__ w2, const float* __restrict__ b2,
    const float* __restrict__ bn_tr, const float* __restrict__ bn_1,
    float* __restrict__ bnpart, float* __restrict__ out1) {
  __shared__ __align__(16) float pool[15556];
  float* Wt = pool;                       // up to 131 rows x stride 65
  float* xin = pool + 8516;               // 131*32 = 4192
  float* ub = xin;                        // alias (xin dead by then)
  float* tb = pool + 8516 + 4192;         // 64*36 = 2304
  float* part = pool + 8516 + 4192 + 2304;  // 512
  int* sknn = (int*)(part + 512);           // 32
  const int bs = blockIdx.x, tid = threadIdx.x;
  const int b = bs >> 10, s = bs & 1023;
  if (tid < K_) sknn[tid] = knn[(size_t)bs * K_ + tid];
  for (int e = tid; e < 64 * 131; e += 256) {
    int o = e / 131, c = e - o * 131;
    Wt[c * 65 + o] = w_tr[e];
  }
  __syncthreads();
  const float inv = invstd[b];
  for (int e = tid; e < CIN_ * K_; e += 256) {
    int c = e >> 5, kk = e & 31;
    float v;
    if (c < 67) {
      int n = sknn[kk];
      float raw = (c < 64) ? feature[((size_t)b * 64 + c) * N_ + n]
                           : xyz[((size_t)b * 3 + (c - 64)) * N_ + n];
      float anc = (c < 64) ? nfeat[(size_t)bs * 64 + c]
                           : nxyz[(size_t)bs * 3 + (c - 64)];
      v = alpha[c] * ((raw - anc) * inv) + beta[c];
    } else {
      v = nfeat[(size_t)bs * 64 + (c - 67)];
    }
    xin[e] = v;
  }
  __syncthreads();
  const int o = tid & 63, kkb = (tid >> 6) * 8;
  float acc[8];
  {
    float bv = b_tr[o];
#pragma unroll
    for (int j = 0; j < 8; j++) acc[j] = bv;
  }
  for (int c = 0; c < CIN_; c++) {
    float w = Wt[c * 65 + o];
    const float4 xa = *(const float4*)(xin + c * 32 + kkb);
    const float4 xb4 = *(const float4*)(xin + c * 32 + kkb + 4);
    acc[0] += w * xa.x; acc[1] += w * xa.y; acc[2] += w * xa.z; acc[3] += w * xa.w;
    acc[4] += w * xb4.x; acc[5] += w * xb4.y; acc[6] += w * xb4.z; acc[7] += w * xb4.w;
  }
  if (MODE == 0) {
    float s8 = 0.f, q8 = 0.f;
#pragma unroll
    for (int j = 0; j < 8; j++) { s8 += acc[j]; q8 += acc[j] * acc[j]; }
    part[(tid >> 6) * 64 + o] = s8;
    part[256 + (tid >> 6) * 64 + o] = q8;
    __syncthreads();
    if (tid < 64) {
      float ss = 0.f, qq = 0.f;
      for (int g = 0; g < 4; g++) { ss += part[g * 64 + tid]; qq += part[256 + g * 64 + tid]; }
      bnpart[(size_t)bs * 128 + tid] = ss;
      bnpart[(size_t)bs * 128 + 64 + tid] = qq;
    }
    return;
  }
  float tv[8];
  {
    float sc = bn_tr[o], sh = bn_tr[64 + o];
#pragma unroll
    for (int j = 0; j < 8; j++) {
      tv[j] = fmaxf(fmaf(sc, acc[j], sh), 0.f);
      tb[o * 36 + kkb + j] = tv[j];
    }
  }
  __syncthreads();
  for (int e = tid; e < 64 * 64; e += 256) {
    int oo = e >> 6, c = e & 63;
    Wt[c * 65 + oo] = w1[e];
  }
  __syncthreads();
  float acc2[8];
  {
    float bv = b1[o];
#pragma unroll
    for (int j = 0; j < 8; j++) acc2[j] = bv;
  }
  for (int c = 0; c < 64; c++) {
    float w = Wt[c * 65 + o];
    const float4 ta = *(const float4*)(tb + c * 36 + kkb);
    const float4 ta2 = *(const float4*)(tb + c * 36 + kkb + 4);
    acc2[0] += w * ta.x; acc2[1] += w * ta.y; acc2[2] += w * ta.z; acc2[3] += w * ta.w;
    acc2[4] += w * ta2.x; acc2[5] += w * ta2.y; acc2[6] += w * ta2.z; acc2[7] += w * ta2.w;
  }
  if (MODE == 1) {
    float s8 = 0.f, q8 = 0.f;
#pragma unroll
    for (int j = 0; j < 8; j++) { s8 += acc2[j]; q8 += acc2[j] * acc2[j]; }
    part[(tid >> 6) * 64 + o] = s8;
    part[256 + (tid >> 6) * 64 + o] = q8;
    __syncthreads();
    if (tid < 64) {
      float ss = 0.f, qq = 0.f;
      for (int g = 0; g < 4; g++) { ss += part[g * 64 + tid]; qq += part[256 + g * 64 + tid]; }
      bnpart[(size_t)bs * 128 + tid] = ss;
      bnpart[(size_t)bs * 128 + 64 + tid] = qq;
    }
    return;
  }
  {
    float sc = bn_1[o], sh = bn_1[64 + o];
#pragma unroll
    for (int j = 0; j < 8; j++) ub[o * 36 + kkb + j] = fmaxf(fmaf(sc, acc2[j], sh), 0.f);
  }
  __syncthreads();
  for (int e = tid; e < 64 * 64; e += 256) {
    int oo = e >> 6, c = e & 63;
    Wt[c * 65 + oo] = w2[e];
  }
  __syncthreads();
  float acc3[8];
  {
    float bv = b2[o];
#pragma unroll
    for (int j = 0; j < 8; j++) acc3[j] = bv;
  }
  for (int c = 0; c < 64; c++) {
    float w = Wt[c * 65 + o];
    const float4 ua = *(const float4*)(ub + c * 36 + kkb);
    const float4 ua2 = *(const float4*)(ub + c * 36 + kkb + 4);
    acc3[0] += w * ua.x; acc3[1] += w * ua.y; acc3[2] += w * ua.z; acc3[3] += w * ua.w;
    acc3[4] += w * ua2.x; acc3[5] += w * ua2.y; acc3[6] += w * ua2.z; acc3[7] += w * ua2.w;
  }
  float m = 0.f;  // relu outputs are >= 0
#pragma unroll
  for (int j = 0; j < 8; j++) m = fmaxf(m, fmaxf(acc3[j] + tv[j], 0.f));
  part[(tid >> 6) * 64 + o] = m;
  __syncthreads();
  if (tid < 64) {
    float mm = part[tid];
    for (int g = 1; g < 4; g++) mm = fmaxf(mm, part[g * 64 + tid]);
    out1[((size_t)b * 64 + tid) * S_ + s] = mm;
  }
}

// ---------------------------------------------------------------------------
extern "C" void kernel_launch(void* const* d_in, const int* in_sizes, int n_in,
                              void* d_out, int out_size, void* d_ws, size_t ws_size,
                              hipStream_t stream) {
  const float* xyz = (const float*)d_in[0];
  const float* feature = (const float*)d_in[1];
  const float* alpha = (const float*)d_in[2];
  const float* beta = (const float*)d_in[3];
  const float* w_tr = (const float*)d_in[4];
  const float* b_tr = (const float*)d_in[5];
  const float* g_tr = (const float*)d_in[6];
  const float* be_tr = (const float*)d_in[7];
  const float* w1 = (const float*)d_in[8];
  const float* b1 = (const float*)d_in[9];
  const float* g1 = (const float*)d_in[10];
  const float* be1 = (const float*)d_in[11];
  const float* w2 = (const float*)d_in[12];
  const float* b2 = (const float*)d_in[13];

  char* ws = (char*)d_ws;
  int* fps_i = (int*)(ws);                      // 32768 B
  float* nxyz = (float*)(ws + 32768);           // 98304 B
  float* nfeat = (float*)(ws + 131072);         // 2097152 B
  int* knn = (int*)(ws + 2228224);              // 1048576 B
  float* stdpart = (float*)(ws + 3276800);      // 4096 B
  float* invstd = (float*)(ws + 3280896);       // 64 B
  float* bn_tr = (float*)(ws + 3280960);        // 512 B
  float* bn_1 = (float*)(ws + 3281472);         // 512 B
  float* bnpart = (float*)(ws + 3281984);       // 4194304 B

  float* out0 = (float*)d_out;
  float* out1 = out0 + B_ * 3 * S_;

  fps_kernel<<<B_, 512, 0, stream>>>(xyz, fps_i, nxyz, out0);
  gather_nf<<<(B_ * S_ * D_) / 256, 256, 0, stream>>>(feature, fps_i, nfeat);
  knn_kernel<<<B_ * S_, 256, 0, stream>>>(xyz, nxyz, knn);
  std_partial<<<B_ * 64, 256, 0, stream>>>(feature, xyz, nxyz, nfeat, knn, stdpart);
  std_final<<<1, 64, 0, stream>>>(stdpart, invstd);
  mlp_kernel<0><<<B_ * S_, 256, 0, stream>>>(feature, xyz, nxyz, nfeat, knn, invstd,
                                             alpha, beta, w_tr, b_tr, w1, b1, w2, b2,
                                             bn_tr, bn_1, bnpart, out1);
  bn_finalize<<<64, 256, 0, stream>>>(bnpart, g_tr, be_tr, bn_tr);
  mlp_kernel<1><<<B_ * S_, 256, 0, stream>>>(feature, xyz, nxyz, nfeat, knn, invstd,
                                             alpha, beta, w_tr, b_tr, w1, b1, w2, b2,
                                             bn_tr, bn_1, bnpart, out1);
  bn_finalize<<<64, 256, 0, stream>>>(bnpart, g1, be1, bn_1);
  mlp_kernel<2><<<B_ * S_, 256, 0, stream>>>(feature, xyz, nxyz, nfeat, knn, invstd,
                                             alpha, beta, w_tr, b_tr, w1, b1, w2, b2,
                                             bn_tr, bn_1, bnpart, out1);
}

// Round 6
// 1854.944 us; speedup vs baseline: 1.3467x; 1.0055x over previous
//
#include <hip/hip_runtime.h>
#include <cfloat>
#include <math.h>

#define B_ 8
#define N_ 4096
#define D_ 64
#define S_ 1024
#define K_ 32
#define CIN_ 131  // 2*D + 3

// Move a u64 across lanes with a constant DPP control (2x 32-bit update_dpp).
template <int CTRL>
__device__ __forceinline__ unsigned long long dpp_u64(unsigned long long k) {
  int lo = (int)(unsigned int)k, hi = (int)(unsigned int)(k >> 32);
  lo = __builtin_amdgcn_update_dpp(lo, lo, CTRL, 0xf, 0xf, false);
  hi = __builtin_amdgcn_update_dpp(hi, hi, CTRL, 0xf, 0xf, false);
  return ((unsigned long long)(unsigned int)hi << 32) | (unsigned int)lo;
}

// Wave(64)-wide float max via DPP (VALU pipe). Result broadcast via readlane 63.
__device__ __forceinline__ float wave_max_f32_dpp(float v) {
  int x = __float_as_int(v);
#define STEP(ctrl)                                                        \
  {                                                                       \
    int t = __builtin_amdgcn_update_dpp(x, x, ctrl, 0xf, 0xf, false);     \
    v = fmaxf(v, __int_as_float(t));                                      \
    x = __float_as_int(v);                                                \
  }
  STEP(0x111)  // row_shr:1
  STEP(0x112)  // row_shr:2
  STEP(0x114)  // row_shr:4
  STEP(0x118)  // row_shr:8
  STEP(0x142)  // row_bcast15
  STEP(0x143)  // row_bcast31
#undef STEP
  return __int_as_float(__builtin_amdgcn_readlane(x, 63));
}

// ---------------------------------------------------------------------------
// FPS (round-5 version — VALIDATED by output-0 pass in round 5): one block
// per batch, 512 threads, thread t owns contiguous [8t,8t+8). Per step:
// local argmax -> DPP wave max + ballot index resolve -> lane-0 writes packed
// u64 winner -> ONE barrier -> each thread reads ONE key (keyp[lane&7]) and
// merges via 3 DPP steps -> next centroid from LDS. No global ops in loop.
// ---------------------------------------------------------------------------
__global__ __launch_bounds__(512) void fps_kernel(const float* __restrict__ xyz,
                                                  int* __restrict__ fps_idx,
                                                  float* __restrict__ nxyz,
                                                  float* __restrict__ out0) {
  const int b = blockIdx.x, tid = threadIdx.x;
  __shared__ __align__(16) float4 sp[N_];    // 64 KB coord mirror
  __shared__ int si[S_];                     // selected indices
  __shared__ unsigned long long keyp[2][8];  // per-wave winners, dbuf
  const float* xb = xyz + (size_t)b * 3 * N_;
  const float4* xv = (const float4*)xb;
  float px[8], py[8], pz[8], dist[8];
  {
    float4 x0 = xv[2 * tid], x1 = xv[2 * tid + 1];
    float4 y0 = xv[1024 + 2 * tid], y1 = xv[1024 + 2 * tid + 1];
    float4 z0 = xv[2048 + 2 * tid], z1 = xv[2048 + 2 * tid + 1];
    px[0] = x0.x; px[1] = x0.y; px[2] = x0.z; px[3] = x0.w;
    px[4] = x1.x; px[5] = x1.y; px[6] = x1.z; px[7] = x1.w;
    py[0] = y0.x; py[1] = y0.y; py[2] = y0.z; py[3] = y0.w;
    py[4] = y1.x; py[5] = y1.y; py[6] = y1.z; py[7] = y1.w;
    pz[0] = z0.x; pz[1] = z0.y; pz[2] = z0.z; pz[3] = z0.w;
    pz[4] = z1.x; pz[5] = z1.y; pz[6] = z1.z; pz[7] = z1.w;
#pragma unroll
    for (int i = 0; i < 8; i++) {
      dist[i] = 1e10f;
      sp[8 * tid + i] = make_float4(px[i], py[i], pz[i], 0.f);
    }
  }
  if (tid == 0) si[0] = 0;
  __syncthreads();
  float cx = sp[0].x, cy = sp[0].y, cz = sp[0].z;
  const int wav = tid >> 6, lane = tid & 63;
  for (int s = 1; s < S_; s++) {
    float best = -1.0f;
    int bi = 8 * tid;
#pragma unroll
    for (int i = 0; i < 8; i++) {
      // no-FMA arithmetic, identical op order to validated rounds
      float dx = __fsub_rn(px[i], cx);
      float dy = __fsub_rn(py[i], cy);
      float dz = __fsub_rn(pz[i], cz);
      float d = __fadd_rn(__fadd_rn(__fmul_rn(dx, dx), __fmul_rn(dy, dy)), __fmul_rn(dz, dz));
      dist[i] = fminf(dist[i], d);
      if (dist[i] > best) { best = dist[i]; bi = 8 * tid + i; }  // strict >: first (smallest) idx
    }
    float wmax = wave_max_f32_dpp(best);
    unsigned long long m = __ballot(best == wmax);
    int l = __ffsll(m) - 1;
    int widx = __builtin_amdgcn_readlane(bi, l);
    if (lane == 0)
      keyp[s & 1][wav] =
          ((unsigned long long)(unsigned int)__float_as_int(wmax) << 32) |
          (unsigned int)(4095 - widx);
    __syncthreads();
    unsigned long long k = keyp[s & 1][lane & 7];
    unsigned long long t;
    t = dpp_u64<0xB1>(k);  if (t > k) k = t;  // quad_perm xor 1
    t = dpp_u64<0x4E>(k);  if (t > k) k = t;  // quad_perm xor 2
    t = dpp_u64<0x124>(k); if (t > k) k = t;  // row_ror:4 (xor 4 on period-8 data)
    int bix = 4095 - (int)(k & 0xfffull);
    if (tid == 0) si[s] = bix;
    float4 c = sp[bix];
    cx = c.x; cy = c.y; cz = c.z;
  }
  __syncthreads();
  for (int e = tid; e < S_; e += 512) {
    int n = si[e];
    fps_idx[b * S_ + e] = n;
    float4 c = sp[n];
    nxyz[(size_t)(b * S_ + e) * 3 + 0] = c.x;
    nxyz[(size_t)(b * S_ + e) * 3 + 1] = c.y;
    nxyz[(size_t)(b * S_ + e) * 3 + 2] = c.z;
    out0[(size_t)b * 3 * S_ + e] = c.x;
    out0[(size_t)b * 3 * S_ + S_ + e] = c.y;
    out0[(size_t)b * 3 * S_ + 2 * S_ + e] = c.z;
  }
}

// ---------------------------------------------------------------------------
// Gather anchor features: nfeat[b,s,c] = feature[b,c,fps_idx[b,s]]
// ---------------------------------------------------------------------------
__global__ __launch_bounds__(256) void gather_nf(const float* __restrict__ feature,
                                                 const int* __restrict__ fps_i,
                                                 float* __restrict__ nfeat) {
  int e = blockIdx.x * 256 + threadIdx.x;  // < B*S*D = 524288
  int b = e >> 16, rem = e & 65535;
  int s = rem >> 6, c = rem & 63;
  int n = fps_i[b * S_ + s];
  nfeat[e] = feature[((size_t)b * 64 + c) * N_ + n];
}

// ---------------------------------------------------------------------------
// kNN: EXACT round-4 version (validated). One block per (b,s) query, 32
// iterative block-argmins with packed-u64 keys via shfl butterfly.
// ---------------------------------------------------------------------------
__global__ __launch_bounds__(256) void knn_kernel(const float* __restrict__ xyz,
                                                  const float* __restrict__ nxyz,
                                                  int* __restrict__ knn) {
  const int bs = blockIdx.x, tid = threadIdx.x;
  const int b = bs >> 10;
  const float* xb = xyz + (size_t)b * 3 * N_;
  const float cx = nxyz[(size_t)bs * 3], cy = nxyz[(size_t)bs * 3 + 1], cz = nxyz[(size_t)bs * 3 + 2];
  const float cn = __fadd_rn(__fadd_rn(__fmul_rn(cx, cx), __fmul_rn(cy, cy)), __fmul_rn(cz, cz));
  float d[16];
#pragma unroll
  for (int i = 0; i < 16; i++) {
    int n = i * 256 + tid;
    float px = xb[n], py = xb[N_ + n], pz = xb[2 * N_ + n];
    float pn = __fadd_rn(__fadd_rn(__fmul_rn(px, px), __fmul_rn(py, py)), __fmul_rn(pz, pz));
    float dot = __fadd_rn(__fadd_rn(__fmul_rn(cx, px), __fmul_rn(cy, py)), __fmul_rn(cz, pz));
    d[i] = __fsub_rn(__fadd_rn(cn, pn), __fmul_rn(2.0f, dot));
  }
  float mv = FLT_MAX;
  int mi = tid;
#pragma unroll
  for (int i = 0; i < 16; i++)
    if (d[i] < mv) { mv = d[i]; mi = i * 256 + tid; }
  __shared__ unsigned long long keyp[2][4];
  __shared__ int skk[K_];
  const int wav = tid >> 6, lane = tid & 63;
  for (int j = 0; j < K_; j++) {
    unsigned int u = __float_as_uint(mv);
    u ^= ((unsigned int)((int)u >> 31) | 0x80000000u);  // monotone map
    unsigned long long key = ((unsigned long long)u << 32) | (unsigned int)mi;
#pragma unroll
    for (int off = 32; off >= 1; off >>= 1) {
      unsigned long long ok = __shfl_xor(key, off);
      if (ok < key) key = ok;
    }
    if (lane == 0) keyp[j & 1][wav] = key;
    __syncthreads();
    unsigned long long kmin = keyp[j & 1][0];
#pragma unroll
    for (int w = 1; w < 4; w++) {
      unsigned long long k2 = keyp[j & 1][w];
      if (k2 < kmin) kmin = k2;
    }
    int g = (int)(kmin & 0xffffffffull);
    if (tid == 0) skk[j] = g;
    if ((g & 255) == tid) {
      int sl = g >> 8;
#pragma unroll
      for (int i = 0; i < 16; i++)
        if (i == sl) d[i] = FLT_MAX;
      mv = FLT_MAX; mi = tid;
#pragma unroll
      for (int i = 0; i < 16; i++)
        if (d[i] < mv) { mv = d[i]; mi = i * 256 + tid; }
    }
  }
  __syncthreads();
  if (tid < K_) knn[(size_t)bs * K_ + tid] = skk[tid];
}

// ---------------------------------------------------------------------------
// Anchor-norm std: per-batch sum/sumsq partials over S*k*67 diffs.
// ---------------------------------------------------------------------------
__global__ __launch_bounds__(256) void std_partial(const float* __restrict__ feature,
                                                   const float* __restrict__ xyz,
                                                   const float* __restrict__ nxyz,
                                                   const float* __restrict__ nfeat,
                                                   const int* __restrict__ knn,
                                                   float* __restrict__ outp) {
  const int blk = blockIdx.x, tid = threadIdx.x;
  const int b = blk >> 6, chunk = blk & 63;
  float s = 0.f, q = 0.f;
  for (int e = tid; e < 16 * K_ * 67; e += 256) {
    int so = e / (K_ * 67);
    int rem = e - so * (K_ * 67);
    int kk = rem / 67;
    int c = rem - kk * 67;
    int bs = b * S_ + chunk * 16 + so;
    int n = knn[(size_t)bs * K_ + kk];
    float raw = (c < 64) ? feature[((size_t)b * 64 + c) * N_ + n]
                         : xyz[((size_t)b * 3 + (c - 64)) * N_ + n];
    float anc = (c < 64) ? nfeat[(size_t)bs * 64 + c]
                         : nxyz[(size_t)bs * 3 + (c - 64)];
    float dd = raw - anc;
    s += dd; q += dd * dd;
  }
#pragma unroll
  for (int off = 32; off >= 1; off >>= 1) { s += __shfl_xor(s, off); q += __shfl_xor(q, off); }
  __shared__ float rs[4], rq[4];
  if ((tid & 63) == 0) { rs[tid >> 6] = s; rq[tid >> 6] = q; }
  __syncthreads();
  if (tid == 0) {
    outp[blk * 2] = rs[0] + rs[1] + rs[2] + rs[3];
    outp[blk * 2 + 1] = rq[0] + rq[1] + rq[2] + rq[3];
  }
}

__global__ void std_final(const float* __restrict__ part, float* __restrict__ invstd) {
  int b = threadIdx.x;
  if (b < B_) {
    double s = 0.0, q = 0.0;
    for (int i = 0; i < 64; i++) {
      s += (double)part[(b * 64 + i) * 2];
      q += (double)part[(b * 64 + i) * 2 + 1];
    }
    const double n = (double)(S_ * K_ * 67);
    double var = (q - s * s / n) / (n - 1.0);  // ddof=1
    invstd[b] = (float)(1.0 / (sqrt(var) + 1e-5));
  }
}

// ---------------------------------------------------------------------------
// BN finalize: per-channel mean/biased-var over 8192 block partials (f64),
// emit fused scale/shift.
// ---------------------------------------------------------------------------
__global__ __launch_bounds__(256) void bn_finalize(const float* __restrict__ part,
                                                   const float* __restrict__ g,
                                                   const float* __restrict__ be,
                                                   float* __restrict__ bnout) {
  const int ch = blockIdx.x, tid = threadIdx.x;
  double s = 0.0, q = 0.0;
  for (int i = tid; i < B_ * S_; i += 256) {
    s += (double)part[(size_t)i * 128 + ch];
    q += (double)part[(size_t)i * 128 + 64 + ch];
  }
#pragma unroll
  for (int off = 32; off >= 1; off >>= 1) { s += __shfl_xor(s, off); q += __shfl_xor(q, off); }
  __shared__ double ls[4], lq[4];
  if ((tid & 63) == 0) { ls[tid >> 6] = s; lq[tid >> 6] = q; }
  __syncthreads();
  if (tid == 0) {
    double Ssum = ls[0] + ls[1] + ls[2] + ls[3];
    double Qsum = lq[0] + lq[1] + lq[2] + lq[3];
    const double n = (double)(B_ * S_ * K_);  // 262144
    double mu = Ssum / n;
    double var = Qsum / n - mu * mu;  // biased (jnp.var default)
    double sc = (double)g[ch] / sqrt(var + 1e-5);
    bnout[ch] = (float)sc;
    bnout[64 + ch] = (float)((double)be[ch] - mu * sc);
  }
}

// ---------------------------------------------------------------------------
// MLP: EXACT round-4 version (validated). One block per (b,s) group.
//   MODE 0: conv_tr -> BN-tr stat partials
//   MODE 1: conv_tr -> bn+relu -> conv1 -> BN-1 stat partials
//   MODE 2: full chain -> residual relu -> max over k -> out
// ---------------------------------------------------------------------------
template <int MODE>
__global__ __launch_bounds__(256, 2) void mlp_kernel(
    const float* __restrict__ feature, const float* __restrict__ xyz,
    const float* __restrict__ nxyz, const float* __restrict__ nfeat,
    const int* __restrict__ knn, const float* __restrict__ invstd,
    const float* __restrict__ alpha, const float* __restrict__ beta,
    const float* __restrict__ w_tr, const float* __restrict__ b_tr,
    const float* __restrict__ w1, const float* __restrict__ b1,
    const float* __restrict__ w2, const float* __restrict__ b2,
    const float* __restrict__ bn_tr, const float* __restrict__ bn_1,
    float* __restrict__ bnpart, float* __restrict__ out1) {
  __shared__ __align__(16) float pool[15556];
  float* Wt = pool;                       // up to 131 rows x stride 65
  float* xin = pool + 8516;               // 131*32 = 4192
  float* ub = xin;                        // alias (xin dead by then)
  float* tb = pool + 8516 + 4192;         // 64*36 = 2304
  float* part = pool + 8516 + 4192 + 2304;  // 512
  int* sknn = (int*)(part + 512);           // 32
  const int bs = blockIdx.x, tid = threadIdx.x;
  const int b = bs >> 10, s = bs & 1023;
  if (tid < K_) sknn[tid] = knn[(size_t)bs * K_ + tid];
  for (int e = tid; e < 64 * 131; e += 256) {
    int o = e / 131, c = e - o * 131;
    Wt[c * 65 + o] = w_tr[e];
  }
  __syncthreads();
  const float inv = invstd[b];
  for (int e = tid; e < CIN_ * K_; e += 256) {
    int c = e >> 5, kk = e & 31;
    float v;
    if (c < 67) {
      int n = sknn[kk];
      float raw = (c < 64) ? feature[((size_t)b * 64 + c) * N_ + n]
                           : xyz[((size_t)b * 3 + (c - 64)) * N_ + n];
      float anc = (c < 64) ? nfeat[(size_t)bs * 64 + c]
                           : nxyz[(size_t)bs * 3 + (c - 64)];
      v = alpha[c] * ((raw - anc) * inv) + beta[c];
    } else {
      v = nfeat[(size_t)bs * 64 + (c - 67)];
    }
    xin[e] = v;
  }
  __syncthreads();
  const int o = tid & 63, kkb = (tid >> 6) * 8;
  float acc[8];
  {
    float bv = b_tr[o];
#pragma unroll
    for (int j = 0; j < 8; j++) acc[j] = bv;
  }
  for (int c = 0; c < CIN_; c++) {
    float w = Wt[c * 65 + o];
    const float4 xa = *(const float4*)(xin + c * 32 + kkb);
    const float4 xb4 = *(const float4*)(xin + c * 32 + kkb + 4);
    acc[0] += w * xa.x; acc[1] += w * xa.y; acc[2] += w * xa.z; acc[3] += w * xa.w;
    acc[4] += w * xb4.x; acc[5] += w * xb4.y; acc[6] += w * xb4.z; acc[7] += w * xb4.w;
  }
  if (MODE == 0) {
    float s8 = 0.f, q8 = 0.f;
#pragma unroll
    for (int j = 0; j < 8; j++) { s8 += acc[j]; q8 += acc[j] * acc[j]; }
    part[(tid >> 6) * 64 + o] = s8;
    part[256 + (tid >> 6) * 64 + o] = q8;
    __syncthreads();
    if (tid < 64) {
      float ss = 0.f, qq = 0.f;
      for (int g = 0; g < 4; g++) { ss += part[g * 64 + tid]; qq += part[256 + g * 64 + tid]; }
      bnpart[(size_t)bs * 128 + tid] = ss;
      bnpart[(size_t)bs * 128 + 64 + tid] = qq;
    }
    return;
  }
  float tv[8];
  {
    float sc = bn_tr[o], sh = bn_tr[64 + o];
#pragma unroll
    for (int j = 0; j < 8; j++) {
      tv[j] = fmaxf(fmaf(sc, acc[j], sh), 0.f);
      tb[o * 36 + kkb + j] = tv[j];
    }
  }
  __syncthreads();
  for (int e = tid; e < 64 * 64; e += 256) {
    int oo = e >> 6, c = e & 63;
    Wt[c * 65 + oo] = w1[e];
  }
  __syncthreads();
  float acc2[8];
  {
    float bv = b1[o];
#pragma unroll
    for (int j = 0; j < 8; j++) acc2[j] = bv;
  }
  for (int c = 0; c < 64; c++) {
    float w = Wt[c * 65 + o];
    const float4 ta = *(const float4*)(tb + c * 36 + kkb);
    const float4 ta2 = *(const float4*)(tb + c * 36 + kkb + 4);
    acc2[0] += w * ta.x; acc2[1] += w * ta.y; acc2[2] += w * ta.z; acc2[3] += w * ta.w;
    acc2[4] += w * ta2.x; acc2[5] += w * ta2.y; acc2[6] += w * ta2.z; acc2[7] += w * ta2.w;
  }
  if (MODE == 1) {
    float s8 = 0.f, q8 = 0.f;
#pragma unroll
    for (int j = 0; j < 8; j++) { s8 += acc2[j]; q8 += acc2[j] * acc2[j]; }
    part[(tid >> 6) * 64 + o] = s8;
    part[256 + (tid >> 6) * 64 + o] = q8;
    __syncthreads();
    if (tid < 64) {
      float ss = 0.f, qq = 0.f;
      for (int g = 0; g < 4; g++) { ss += part[g * 64 + tid]; qq += part[256 + g * 64 + tid]; }
      bnpart[(size_t)bs * 128 + tid] = ss;
      bnpart[(size_t)bs * 128 + 64 + tid] = qq;
    }
    return;
  }
  {
    float sc = bn_1[o], sh = bn_1[64 + o];
#pragma unroll
    for (int j = 0; j < 8; j++) ub[o * 36 + kkb + j] = fmaxf(fmaf(sc, acc2[j], sh), 0.f);
  }
  __syncthreads();
  for (int e = tid; e < 64 * 64; e += 256) {
    int oo = e >> 6, c = e & 63;
    Wt[c * 65 + oo] = w2[e];
  }
  __syncthreads();
  float acc3[8];
  {
    float bv = b2[o];
#pragma unroll
    for (int j = 0; j < 8; j++) acc3[j] = bv;
  }
  for (int c = 0; c < 64; c++) {
    float w = Wt[c * 65 + o];
    const float4 ua = *(const float4*)(ub + c * 36 + kkb);
    const float4 ua2 = *(const float4*)(ub + c * 36 + kkb + 4);
    acc3[0] += w * ua.x; acc3[1] += w * ua.y; acc3[2] += w * ua.z; acc3[3] += w * ua.w;
    acc3[4] += w * ua2.x; acc3[5] += w * ua2.y; acc3[6] += w * ua2.z; acc3[7] += w * ua2.w;
  }
  float m = 0.f;  // relu outputs are >= 0
#pragma unroll
  for (int j = 0; j < 8; j++) m = fmaxf(m, fmaxf(acc3[j] + tv[j], 0.f));
  part[(tid >> 6) * 64 + o] = m;
  __syncthreads();
  if (tid < 64) {
    float mm = part[tid];
    for (int g = 1; g < 4; g++) mm = fmaxf(mm, part[g * 64 + tid]);
    out1[((size_t)b * 64 + tid) * S_ + s] = mm;
  }
}

// ---------------------------------------------------------------------------
extern "C" void kernel_launch(void* const* d_in, const int* in_sizes, int n_in,
                              void* d_out, int out_size, void* d_ws, size_t ws_size,
                              hipStream_t stream) {
  const float* xyz = (const float*)d_in[0];
  const float* feature = (const float*)d_in[1];
  const float* alpha = (const float*)d_in[2];
  const float* beta = (const float*)d_in[3];
  const float* w_tr = (const float*)d_in[4];
  const float* b_tr = (const float*)d_in[5];
  const float* g_tr = (const float*)d_in[6];
  const float* be_tr = (const float*)d_in[7];
  const float* w1 = (const float*)d_in[8];
  const float* b1 = (const float*)d_in[9];
  const float* g1 = (const float*)d_in[10];
  const float* be1 = (const float*)d_in[11];
  const float* w2 = (const float*)d_in[12];
  const float* b2 = (const float*)d_in[13];

  char* ws = (char*)d_ws;
  int* fps_i = (int*)(ws);                      // 32768 B
  float* nxyz = (float*)(ws + 32768);           // 98304 B
  float* nfeat = (float*)(ws + 131072);         // 2097152 B
  int* knn = (int*)(ws + 2228224);              // 1048576 B
  float* stdpart = (float*)(ws + 3276800);      // 4096 B
  float* invstd = (float*)(ws + 3280896);       // 64 B
  float* bn_tr = (float*)(ws + 3280960);        // 512 B
  float* bn_1 = (float*)(ws + 3281472);         // 512 B
  float* bnpart = (float*)(ws + 3281984);       // 4194304 B

  float* out0 = (float*)d_out;
  float* out1 = out0 + B_ * 3 * S_;

  fps_kernel<<<B_, 512, 0, stream>>>(xyz, fps_i, nxyz, out0);
  gather_nf<<<(B_ * S_ * D_) / 256, 256, 0, stream>>>(feature, fps_i, nfeat);
  knn_kernel<<<B_ * S_, 256, 0, stream>>>(xyz, nxyz, knn);
  std_partial<<<B_ * 64, 256, 0, stream>>>(feature, xyz, nxyz, nfeat, knn, stdpart);
  std_final<<<1, 64, 0, stream>>>(stdpart, invstd);
  mlp_kernel<0><<<B_ * S_, 256, 0, stream>>>(feature, xyz, nxyz, nfeat, knn, invstd,
                                             alpha, beta, w_tr, b_tr, w1, b1, w2, b2,
                                             bn_tr, bn_1, bnpart, out1);
  bn_finalize<<<64, 256, 0, stream>>>(bnpart, g_tr, be_tr, bn_tr);
  mlp_kernel<1><<<B_ * S_, 256, 0, stream>>>(feature, xyz, nxyz, nfeat, knn, invstd,
                                             alpha, beta, w_tr, b_tr, w1, b1, w2, b2,
                                             bn_tr, bn_1, bnpart, out1);
  bn_finalize<<<64, 256, 0, stream>>>(bnpart, g1, be1, bn_1);
  mlp_kernel<2><<<B_ * S_, 256, 0, stream>>>(feature, xyz, nxyz, nfeat, knn, invstd,
                                             alpha, beta, w_tr, b_tr, w1, b1, w2, b2,
                                             bn_tr, bn_1, bnpart, out1);
}

// Round 7
// 1196.346 us; speedup vs baseline: 2.0880x; 1.5505x over previous
//
#include <hip/hip_runtime.h>
#include <cfloat>
#include <math.h>

#define B_ 8
#define N_ 4096
#define D_ 64
#define S_ 1024
#define K_ 32
#define CIN_ 131  // 2*D + 3

// Move a u64 across lanes with a constant DPP control (2x 32-bit update_dpp).
template <int CTRL>
__device__ __forceinline__ unsigned long long dpp_u64(unsigned long long k) {
  int lo = (int)(unsigned int)k, hi = (int)(unsigned int)(k >> 32);
  lo = __builtin_amdgcn_update_dpp(lo, lo, CTRL, 0xf, 0xf, false);
  hi = __builtin_amdgcn_update_dpp(hi, hi, CTRL, 0xf, 0xf, false);
  return ((unsigned long long)(unsigned int)hi << 32) | (unsigned int)lo;
}

// Wave(64)-wide float max via DPP (VALU pipe). Result broadcast via readlane 63.
__device__ __forceinline__ float wave_max_f32_dpp(float v) {
  int x = __float_as_int(v);
#define STEP(ctrl)                                                        \
  {                                                                       \
    int t = __builtin_amdgcn_update_dpp(x, x, ctrl, 0xf, 0xf, false);     \
    v = fmaxf(v, __int_as_float(t));                                      \
    x = __float_as_int(v);                                                \
  }
  STEP(0x111)
  STEP(0x112)
  STEP(0x114)
  STEP(0x118)
  STEP(0x142)
  STEP(0x143)
#undef STEP
  return __int_as_float(__builtin_amdgcn_readlane(x, 63));
}

// ---------------------------------------------------------------------------
// FPS (validated r5/r6 version — unchanged).
// ---------------------------------------------------------------------------
__global__ __launch_bounds__(512) void fps_kernel(const float* __restrict__ xyz,
                                                  int* __restrict__ fps_idx,
                                                  float* __restrict__ nxyz,
                                                  float* __restrict__ out0) {
  const int b = blockIdx.x, tid = threadIdx.x;
  __shared__ __align__(16) float4 sp[N_];
  __shared__ int si[S_];
  __shared__ unsigned long long keyp[2][8];
  const float* xb = xyz + (size_t)b * 3 * N_;
  const float4* xv = (const float4*)xb;
  float px[8], py[8], pz[8], dist[8];
  {
    float4 x0 = xv[2 * tid], x1 = xv[2 * tid + 1];
    float4 y0 = xv[1024 + 2 * tid], y1 = xv[1024 + 2 * tid + 1];
    float4 z0 = xv[2048 + 2 * tid], z1 = xv[2048 + 2 * tid + 1];
    px[0] = x0.x; px[1] = x0.y; px[2] = x0.z; px[3] = x0.w;
    px[4] = x1.x; px[5] = x1.y; px[6] = x1.z; px[7] = x1.w;
    py[0] = y0.x; py[1] = y0.y; py[2] = y0.z; py[3] = y0.w;
    py[4] = y1.x; py[5] = y1.y; py[6] = y1.z; py[7] = y1.w;
    pz[0] = z0.x; pz[1] = z0.y; pz[2] = z0.z; pz[3] = z0.w;
    pz[4] = z1.x; pz[5] = z1.y; pz[6] = z1.z; pz[7] = z1.w;
#pragma unroll
    for (int i = 0; i < 8; i++) {
      dist[i] = 1e10f;
      sp[8 * tid + i] = make_float4(px[i], py[i], pz[i], 0.f);
    }
  }
  if (tid == 0) si[0] = 0;
  __syncthreads();
  float cx = sp[0].x, cy = sp[0].y, cz = sp[0].z;
  const int wav = tid >> 6, lane = tid & 63;
  for (int s = 1; s < S_; s++) {
    float best = -1.0f;
    int bi = 8 * tid;
#pragma unroll
    for (int i = 0; i < 8; i++) {
      float dx = __fsub_rn(px[i], cx);
      float dy = __fsub_rn(py[i], cy);
      float dz = __fsub_rn(pz[i], cz);
      float d = __fadd_rn(__fadd_rn(__fmul_rn(dx, dx), __fmul_rn(dy, dy)), __fmul_rn(dz, dz));
      dist[i] = fminf(dist[i], d);
      if (dist[i] > best) { best = dist[i]; bi = 8 * tid + i; }
    }
    float wmax = wave_max_f32_dpp(best);
    unsigned long long m = __ballot(best == wmax);
    int l = __ffsll(m) - 1;
    int widx = __builtin_amdgcn_readlane(bi, l);
    if (lane == 0)
      keyp[s & 1][wav] =
          ((unsigned long long)(unsigned int)__float_as_int(wmax) << 32) |
          (unsigned int)(4095 - widx);
    __syncthreads();
    unsigned long long k = keyp[s & 1][lane & 7];
    unsigned long long t;
    t = dpp_u64<0xB1>(k);  if (t > k) k = t;
    t = dpp_u64<0x4E>(k);  if (t > k) k = t;
    t = dpp_u64<0x124>(k); if (t > k) k = t;
    int bix = 4095 - (int)(k & 0xfffull);
    if (tid == 0) si[s] = bix;
    float4 c = sp[bix];
    cx = c.x; cy = c.y; cz = c.z;
  }
  __syncthreads();
  for (int e = tid; e < S_; e += 512) {
    int n = si[e];
    fps_idx[b * S_ + e] = n;
    float4 c = sp[n];
    nxyz[(size_t)(b * S_ + e) * 3 + 0] = c.x;
    nxyz[(size_t)(b * S_ + e) * 3 + 1] = c.y;
    nxyz[(size_t)(b * S_ + e) * 3 + 2] = c.z;
    out0[(size_t)b * 3 * S_ + e] = c.x;
    out0[(size_t)b * 3 * S_ + S_ + e] = c.y;
    out0[(size_t)b * 3 * S_ + 2 * S_ + e] = c.z;
  }
}

// ---------------------------------------------------------------------------
// kNN (validated r4/r6 version — unchanged).
// ---------------------------------------------------------------------------
__global__ __launch_bounds__(256) void knn_kernel(const float* __restrict__ xyz,
                                                  const float* __restrict__ nxyz,
                                                  int* __restrict__ knn) {
  const int bs = blockIdx.x, tid = threadIdx.x;
  const int b = bs >> 10;
  const float* xb = xyz + (size_t)b * 3 * N_;
  const float cx = nxyz[(size_t)bs * 3], cy = nxyz[(size_t)bs * 3 + 1], cz = nxyz[(size_t)bs * 3 + 2];
  const float cn = __fadd_rn(__fadd_rn(__fmul_rn(cx, cx), __fmul_rn(cy, cy)), __fmul_rn(cz, cz));
  float d[16];
#pragma unroll
  for (int i = 0; i < 16; i++) {
    int n = i * 256 + tid;
    float px = xb[n], py = xb[N_ + n], pz = xb[2 * N_ + n];
    float pn = __fadd_rn(__fadd_rn(__fmul_rn(px, px), __fmul_rn(py, py)), __fmul_rn(pz, pz));
    float dot = __fadd_rn(__fadd_rn(__fmul_rn(cx, px), __fmul_rn(cy, py)), __fmul_rn(cz, pz));
    d[i] = __fsub_rn(__fadd_rn(cn, pn), __fmul_rn(2.0f, dot));
  }
  float mv = FLT_MAX;
  int mi = tid;
#pragma unroll
  for (int i = 0; i < 16; i++)
    if (d[i] < mv) { mv = d[i]; mi = i * 256 + tid; }
  __shared__ unsigned long long keyp[2][4];
  __shared__ int skk[K_];
  const int wav = tid >> 6, lane = tid & 63;
  for (int j = 0; j < K_; j++) {
    unsigned int u = __float_as_uint(mv);
    u ^= ((unsigned int)((int)u >> 31) | 0x80000000u);
    unsigned long long key = ((unsigned long long)u << 32) | (unsigned int)mi;
#pragma unroll
    for (int off = 32; off >= 1; off >>= 1) {
      unsigned long long ok = __shfl_xor(key, off);
      if (ok < key) key = ok;
    }
    if (lane == 0) keyp[j & 1][wav] = key;
    __syncthreads();
    unsigned long long kmin = keyp[j & 1][0];
#pragma unroll
    for (int w = 1; w < 4; w++) {
      unsigned long long k2 = keyp[j & 1][w];
      if (k2 < kmin) kmin = k2;
    }
    int g = (int)(kmin & 0xffffffffull);
    if (tid == 0) skk[j] = g;
    if ((g & 255) == tid) {
      int sl = g >> 8;
#pragma unroll
      for (int i = 0; i < 16; i++)
        if (i == sl) d[i] = FLT_MAX;
      mv = FLT_MAX; mi = tid;
#pragma unroll
      for (int i = 0; i < 16; i++)
        if (d[i] < mv) { mv = d[i]; mi = i * 256 + tid; }
    }
  }
  __syncthreads();
  if (tid < K_) knn[(size_t)bs * K_ + tid] = skk[tid];
}

// ===========================================================================
// ============ FALLBACK (r6) kernels — used when ws is small ================
// ===========================================================================
__global__ __launch_bounds__(256) void gather_nf(const float* __restrict__ feature,
                                                 const int* __restrict__ fps_i,
                                                 float* __restrict__ nfeat) {
  int e = blockIdx.x * 256 + threadIdx.x;
  int b = e >> 16, rem = e & 65535;
  int s = rem >> 6, c = rem & 63;
  int n = fps_i[b * S_ + s];
  nfeat[e] = feature[((size_t)b * 64 + c) * N_ + n];
}

__global__ __launch_bounds__(256) void std_partial(const float* __restrict__ feature,
                                                   const float* __restrict__ xyz,
                                                   const float* __restrict__ nxyz,
                                                   const float* __restrict__ nfeat,
                                                   const int* __restrict__ knn,
                                                   float* __restrict__ outp) {
  const int blk = blockIdx.x, tid = threadIdx.x;
  const int b = blk >> 6, chunk = blk & 63;
  float s = 0.f, q = 0.f;
  for (int e = tid; e < 16 * K_ * 67; e += 256) {
    int so = e / (K_ * 67);
    int rem = e - so * (K_ * 67);
    int kk = rem / 67;
    int c = rem - kk * 67;
    int bs = b * S_ + chunk * 16 + so;
    int n = knn[(size_t)bs * K_ + kk];
    float raw = (c < 64) ? feature[((size_t)b * 64 + c) * N_ + n]
                         : xyz[((size_t)b * 3 + (c - 64)) * N_ + n];
    float anc = (c < 64) ? nfeat[(size_t)bs * 64 + c]
                         : nxyz[(size_t)bs * 3 + (c - 64)];
    float dd = raw - anc;
    s += dd; q += dd * dd;
  }
#pragma unroll
  for (int off = 32; off >= 1; off >>= 1) { s += __shfl_xor(s, off); q += __shfl_xor(q, off); }
  __shared__ float rs[4], rq[4];
  if ((tid & 63) == 0) { rs[tid >> 6] = s; rq[tid >> 6] = q; }
  __syncthreads();
  if (tid == 0) {
    outp[blk * 2] = rs[0] + rs[1] + rs[2] + rs[3];
    outp[blk * 2 + 1] = rq[0] + rq[1] + rq[2] + rq[3];
  }
}

__global__ void std_final(const float* __restrict__ part, float* __restrict__ invstd) {
  int b = threadIdx.x;
  if (b < B_) {
    double s = 0.0, q = 0.0;
    for (int i = 0; i < 64; i++) {
      s += (double)part[(b * 64 + i) * 2];
      q += (double)part[(b * 64 + i) * 2 + 1];
    }
    const double n = (double)(S_ * K_ * 67);
    double var = (q - s * s / n) / (n - 1.0);
    invstd[b] = (float)(1.0 / (sqrt(var) + 1e-5));
  }
}

template <int MODE>
__global__ __launch_bounds__(256, 2) void mlp_kernel(
    const float* __restrict__ feature, const float* __restrict__ xyz,
    const float* __restrict__ nxyz, const float* __restrict__ nfeat,
    const int* __restrict__ knn, const float* __restrict__ invstd,
    const float* __restrict__ alpha, const float* __restrict__ beta,
    const float* __restrict__ w_tr, const float* __restrict__ b_tr,
    const float* __restrict__ w1, const float* __restrict__ b1,
    const float* __restrict__ w2, const float* __restrict__ b2,
    const float* __restrict__ bn_tr, const float* __restrict__ bn_1,
    float* __restrict__ bnpart, float* __restrict__ out1) {
  __shared__ __align__(16) float pool[15556];
  float* Wt = pool;
  float* xin = pool + 8516;
  float* ub = xin;
  float* tb = pool + 8516 + 4192;
  float* part = pool + 8516 + 4192 + 2304;
  int* sknn = (int*)(part + 512);
  const int bs = blockIdx.x, tid = threadIdx.x;
  const int b = bs >> 10, s = bs & 1023;
  if (tid < K_) sknn[tid] = knn[(size_t)bs * K_ + tid];
  for (int e = tid; e < 64 * 131; e += 256) {
    int o = e / 131, c = e - o * 131;
    Wt[c * 65 + o] = w_tr[e];
  }
  __syncthreads();
  const float inv = invstd[b];
  for (int e = tid; e < CIN_ * K_; e += 256) {
    int c = e >> 5, kk = e & 31;
    float v;
    if (c < 67) {
      int n = sknn[kk];
      float raw = (c < 64) ? feature[((size_t)b * 64 + c) * N_ + n]
                           : xyz[((size_t)b * 3 + (c - 64)) * N_ + n];
      float anc = (c < 64) ? nfeat[(size_t)bs * 64 + c]
                           : nxyz[(size_t)bs * 3 + (c - 64)];
      v = alpha[c] * ((raw - anc) * inv) + beta[c];
    } else {
      v = nfeat[(size_t)bs * 64 + (c - 67)];
    }
    xin[e] = v;
  }
  __syncthreads();
  const int o = tid & 63, kkb = (tid >> 6) * 8;
  float acc[8];
  {
    float bv = b_tr[o];
#pragma unroll
    for (int j = 0; j < 8; j++) acc[j] = bv;
  }
  for (int c = 0; c < CIN_; c++) {
    float w = Wt[c * 65 + o];
    const float4 xa = *(const float4*)(xin + c * 32 + kkb);
    const float4 xb4 = *(const float4*)(xin + c * 32 + kkb + 4);
    acc[0] += w * xa.x; acc[1] += w * xa.y; acc[2] += w * xa.z; acc[3] += w * xa.w;
    acc[4] += w * xb4.x; acc[5] += w * xb4.y; acc[6] += w * xb4.z; acc[7] += w * xb4.w;
  }
  if (MODE == 0) {
    float s8 = 0.f, q8 = 0.f;
#pragma unroll
    for (int j = 0; j < 8; j++) { s8 += acc[j]; q8 += acc[j] * acc[j]; }
    part[(tid >> 6) * 64 + o] = s8;
    part[256 + (tid >> 6) * 64 + o] = q8;
    __syncthreads();
    if (tid < 64) {
      float ss = 0.f, qq = 0.f;
      for (int g = 0; g < 4; g++) { ss += part[g * 64 + tid]; qq += part[256 + g * 64 + tid]; }
      bnpart[(size_t)bs * 128 + tid] = ss;
      bnpart[(size_t)bs * 128 + 64 + tid] = qq;
    }
    return;
  }
  float tv[8];
  {
    float sc = bn_tr[o], sh = bn_tr[64 + o];
#pragma unroll
    for (int j = 0; j < 8; j++) {
      tv[j] = fmaxf(fmaf(sc, acc[j], sh), 0.f);
      tb[o * 36 + kkb + j] = tv[j];
    }
  }
  __syncthreads();
  for (int e = tid; e < 64 * 64; e += 256) {
    int oo = e >> 6, c = e & 63;
    Wt[c * 65 + oo] = w1[e];
  }
  __syncthreads();
  float acc2[8];
  {
    float bv = b1[o];
#pragma unroll
    for (int j = 0; j < 8; j++) acc2[j] = bv;
  }
  for (int c = 0; c < 64; c++) {
    float w = Wt[c * 65 + o];
    const float4 ta = *(const float4*)(tb + c * 36 + kkb);
    const float4 ta2 = *(const float4*)(tb + c * 36 + kkb + 4);
    acc2[0] += w * ta.x; acc2[1] += w * ta.y; acc2[2] += w * ta.z; acc2[3] += w * ta.w;
    acc2[4] += w * ta2.x; acc2[5] += w * ta2.y; acc2[6] += w * ta2.z; acc2[7] += w * ta2.w;
  }
  if (MODE == 1) {
    float s8 = 0.f, q8 = 0.f;
#pragma unroll
    for (int j = 0; j < 8; j++) { s8 += acc2[j]; q8 += acc2[j] * acc2[j]; }
    part[(tid >> 6) * 64 + o] = s8;
    part[256 + (tid >> 6) * 64 + o] = q8;
    __syncthreads();
    if (tid < 64) {
      float ss = 0.f, qq = 0.f;
      for (int g = 0; g < 4; g++) { ss += part[g * 64 + tid]; qq += part[256 + g * 64 + tid]; }
      bnpart[(size_t)bs * 128 + tid] = ss;
      bnpart[(size_t)bs * 128 + 64 + tid] = qq;
    }
    return;
  }
  {
    float sc = bn_1[o], sh = bn_1[64 + o];
#pragma unroll
    for (int j = 0; j < 8; j++) ub[o * 36 + kkb + j] = fmaxf(fmaf(sc, acc2[j], sh), 0.f);
  }
  __syncthreads();
  for (int e = tid; e < 64 * 64; e += 256) {
    int oo = e >> 6, c = e & 63;
    Wt[c * 65 + oo] = w2[e];
  }
  __syncthreads();
  float acc3[8];
  {
    float bv = b2[o];
#pragma unroll
    for (int j = 0; j < 8; j++) acc3[j] = bv;
  }
  for (int c = 0; c < 64; c++) {
    float w = Wt[c * 65 + o];
    const float4 ua = *(const float4*)(ub + c * 36 + kkb);
    const float4 ua2 = *(const float4*)(ub + c * 36 + kkb + 4);
    acc3[0] += w * ua.x; acc3[1] += w * ua.y; acc3[2] += w * ua.z; acc3[3] += w * ua.w;
    acc3[4] += w * ua2.x; acc3[5] += w * ua2.y; acc3[6] += w * ua2.z; acc3[7] += w * ua2.w;
  }
  float m = 0.f;
#pragma unroll
  for (int j = 0; j < 8; j++) m = fmaxf(m, fmaxf(acc3[j] + tv[j], 0.f));
  part[(tid >> 6) * 64 + o] = m;
  __syncthreads();
  if (tid < 64) {
    float mm = part[tid];
    for (int g = 1; g < 4; g++) mm = fmaxf(mm, part[g * 64 + tid]);
    out1[((size_t)b * 64 + tid) * S_ + s] = mm;
  }
}

// ---------------------------------------------------------------------------
// BN finalize (shared by both paths).
// ---------------------------------------------------------------------------
__global__ __launch_bounds__(256) void bn_finalize(const float* __restrict__ part,
                                                   const float* __restrict__ g,
                                                   const float* __restrict__ be,
                                                   float* __restrict__ bnout) {
  const int ch = blockIdx.x, tid = threadIdx.x;
  double s = 0.0, q = 0.0;
  for (int i = tid; i < B_ * S_; i += 256) {
    s += (double)part[(size_t)i * 128 + ch];
    q += (double)part[(size_t)i * 128 + 64 + ch];
  }
#pragma unroll
  for (int off = 32; off >= 1; off >>= 1) { s += __shfl_xor(s, off); q += __shfl_xor(q, off); }
  __shared__ double ls[4], lq[4];
  if ((tid & 63) == 0) { ls[tid >> 6] = s; lq[tid >> 6] = q; }
  __syncthreads();
  if (tid == 0) {
    double Ssum = ls[0] + ls[1] + ls[2] + ls[3];
    double Qsum = lq[0] + lq[1] + lq[2] + lq[3];
    const double n = (double)(B_ * S_ * K_);
    double mu = Ssum / n;
    double var = Qsum / n - mu * mu;
    double sc = (double)g[ch] / sqrt(var + 1e-5);
    bnout[ch] = (float)sc;
    bnout[64 + ch] = (float)((double)be[ch] - mu * sc);
  }
}

// ===========================================================================
// ================== CACHE-PATH kernels (large workspace) ===================
// ===========================================================================

// Transpose feature [b][c][n] -> featT [b][n][c] (coalesced gathers later).
__global__ __launch_bounds__(256) void transpose_feat(const float* __restrict__ feature,
                                                      float* __restrict__ featT) {
  __shared__ float tile[64 * 65];
  const int blk = blockIdx.x, tid = threadIdx.x;
  const int b = blk >> 6, n0 = (blk & 63) * 64;
#pragma unroll
  for (int i = 0; i < 16; i++) {
    int c = i * 4 + (tid >> 6), nl = tid & 63;
    tile[c * 65 + nl] = feature[((size_t)b * 64 + c) * N_ + n0 + nl];
  }
  __syncthreads();
#pragma unroll
  for (int i = 0; i < 16; i++) {
    int nl = i * 4 + (tid >> 6), c = tid & 63;
    featT[((size_t)b * N_ + n0 + nl) * 64 + c] = tile[c * 65 + nl];
  }
}

// Anchor features via featT (coalesced read & write).
__global__ __launch_bounds__(256) void gather_nf_c(const float* __restrict__ featT,
                                                   const int* __restrict__ fps_i,
                                                   float* __restrict__ nfeat) {
  int e = blockIdx.x * 256 + threadIdx.x;  // < B*S*D
  int bs = e >> 6, c = e & 63;
  int b = bs >> 10;
  int n = fps_i[bs];
  nfeat[e] = featT[((size_t)b * N_ + n) * 64 + c];
}

// Fused diff computation + std partials. 1024 blocks x 8 groups.
// dcache[bs][kk][c] (stride 68) holds raw-anchor diffs for c in [0,67).
__global__ __launch_bounds__(256) void prep_kernel(const float* __restrict__ featT,
                                                   const float* __restrict__ xyz,
                                                   const float* __restrict__ nxyz,
                                                   const float* __restrict__ nfeat,
                                                   const int* __restrict__ knn,
                                                   float* __restrict__ dcache,
                                                   float* __restrict__ outp) {
  const int blk = blockIdx.x, tid = threadIdx.x;
  __shared__ int sk[32];
  float s = 0.f, q = 0.f;
  const int c = tid & 63, qd = tid >> 6;
  for (int g = 0; g < 8; g++) {
    const int bs = blk * 8 + g, b = bs >> 10;
    if (tid < 32) sk[tid] = knn[(size_t)bs * K_ + tid];
    __syncthreads();
    float anc = nfeat[(size_t)bs * 64 + c];
#pragma unroll
    for (int it = 0; it < 8; it++) {
      int kk = it * 4 + qd;
      int n = sk[kk];
      float dd = featT[((size_t)b * N_ + n) * 64 + c] - anc;
      s += dd; q += dd * dd;
      dcache[((size_t)bs * 32 + kk) * 68 + c] = dd;
    }
    if (tid < 96) {
      int c3 = tid >> 5, kk = tid & 31;
      int n = sk[kk];
      float dd = xyz[((size_t)b * 3 + c3) * N_ + n] - nxyz[(size_t)bs * 3 + c3];
      s += dd; q += dd * dd;
      dcache[((size_t)bs * 32 + kk) * 68 + 64 + c3] = dd;
    }
    __syncthreads();
  }
#pragma unroll
  for (int off = 32; off >= 1; off >>= 1) { s += __shfl_xor(s, off); q += __shfl_xor(q, off); }
  __shared__ float rs[4], rq[4];
  if ((tid & 63) == 0) { rs[tid >> 6] = s; rq[tid >> 6] = q; }
  __syncthreads();
  if (tid == 0) {
    outp[blk * 2] = rs[0] + rs[1] + rs[2] + rs[3];
    outp[blk * 2 + 1] = rq[0] + rq[1] + rq[2] + rq[3];
  }
}

__global__ void std_final_c(const float* __restrict__ part, float* __restrict__ invstd) {
  int b = threadIdx.x;
  if (b < B_) {
    double s = 0.0, q = 0.0;
    for (int i = 0; i < 128; i++) {
      s += (double)part[(b * 128 + i) * 2];
      q += (double)part[(b * 128 + i) * 2 + 1];
    }
    const double n = (double)(S_ * K_ * 67);
    double var = (q - s * s / n) / (n - 1.0);
    invstd[b] = (float)(1.0 / (sqrt(var) + 1e-5));
  }
}

// MLP stage 0: xin from dcache (coalesced), conv_tr, stats + tcache store.
__global__ __launch_bounds__(256, 2) void mlp0c(
    const float* __restrict__ dcache, const float* __restrict__ nfeat,
    const float* __restrict__ invstd,
    const float* __restrict__ alpha, const float* __restrict__ beta,
    const float* __restrict__ w_tr, const float* __restrict__ b_tr,
    float* __restrict__ bnpart, float* __restrict__ tcache) {
  __shared__ __align__(16) float pool[13220];
  float* Wt = pool;          // 131 x 65 = 8515 (+1)
  float* xin = pool + 8516;  // 131*32 = 4192
  float* part = pool + 8516 + 4192;  // 512
  const int bs = blockIdx.x, tid = threadIdx.x;
  const int b = bs >> 10;
  for (int e = tid; e < 64 * 131; e += 256) {
    int o = e / 131, c = e - o * 131;
    Wt[c * 65 + o] = w_tr[e];
  }
  const float inv = invstd[b];
  {
    const int c = tid & 63, qd = tid >> 6;
    float al = alpha[c], bev = beta[c];
#pragma unroll
    for (int it = 0; it < 8; it++) {
      int kk = it * 4 + qd;
      xin[c * 32 + kk] = al * (dcache[((size_t)bs * 32 + kk) * 68 + c] * inv) + bev;
    }
    if (tid < 96) {
      int c3 = 64 + (tid >> 5), kk = tid & 31;
      xin[c3 * 32 + kk] =
          alpha[c3] * (dcache[((size_t)bs * 32 + kk) * 68 + c3] * inv) + beta[c3];
    }
    for (int e = tid; e < 2048; e += 256) {
      int cc = 67 + (e >> 5), kk = e & 31;
      xin[cc * 32 + kk] = nfeat[(size_t)bs * 64 + (e >> 5)];
    }
  }
  __syncthreads();
  const int o = tid & 63, kkb = (tid >> 6) * 8;
  float acc[8];
  {
    float bv = b_tr[o];
#pragma unroll
    for (int j = 0; j < 8; j++) acc[j] = bv;
  }
  for (int c = 0; c < CIN_; c++) {
    float w = Wt[c * 65 + o];
    const float4 xa = *(const float4*)(xin + c * 32 + kkb);
    const float4 xb4 = *(const float4*)(xin + c * 32 + kkb + 4);
    acc[0] += w * xa.x; acc[1] += w * xa.y; acc[2] += w * xa.z; acc[3] += w * xa.w;
    acc[4] += w * xb4.x; acc[5] += w * xb4.y; acc[6] += w * xb4.z; acc[7] += w * xb4.w;
  }
  // store raw conv_tr output
  {
    float4* tp = (float4*)(tcache + ((size_t)bs * 64 + o) * 32 + kkb);
    tp[0] = make_float4(acc[0], acc[1], acc[2], acc[3]);
    tp[1] = make_float4(acc[4], acc[5], acc[6], acc[7]);
  }
  float s8 = 0.f, q8 = 0.f;
#pragma unroll
  for (int j = 0; j < 8; j++) { s8 += acc[j]; q8 += acc[j] * acc[j]; }
  part[(tid >> 6) * 64 + o] = s8;
  part[256 + (tid >> 6) * 64 + o] = q8;
  __syncthreads();
  if (tid < 64) {
    float ss = 0.f, qq = 0.f;
    for (int g = 0; g < 4; g++) { ss += part[g * 64 + tid]; qq += part[256 + g * 64 + tid]; }
    bnpart[(size_t)bs * 128 + tid] = ss;
    bnpart[(size_t)bs * 128 + 64 + tid] = qq;
  }
}

// MLP stage 1: t = bn+relu(tcache); conv1; stats + ucache store.
__global__ __launch_bounds__(256, 3) void mlp1c(
    const float* __restrict__ tcache, const float* __restrict__ bn_tr,
    const float* __restrict__ w1, const float* __restrict__ b1,
    float* __restrict__ bnpart, float* __restrict__ ucache) {
  __shared__ __align__(16) float pool[6976];
  float* Wt = pool;               // 64 x 65 = 4160
  float* tb = pool + 4160;        // 64*36 = 2304
  float* part = pool + 4160 + 2304;  // 512
  const int bs = blockIdx.x, tid = threadIdx.x;
  const int o = tid & 63, kkb = (tid >> 6) * 8;
  for (int e = tid; e < 64 * 64; e += 256) {
    int oo = e >> 6, c = e & 63;
    Wt[c * 65 + oo] = w1[e];
  }
  float t[8];
  {
    const float4* tp = (const float4*)(tcache + ((size_t)bs * 64 + o) * 32 + kkb);
    float4 a = tp[0], b4 = tp[1];
    t[0] = a.x; t[1] = a.y; t[2] = a.z; t[3] = a.w;
    t[4] = b4.x; t[5] = b4.y; t[6] = b4.z; t[7] = b4.w;
  }
  {
    float sc = bn_tr[o], sh = bn_tr[64 + o];
#pragma unroll
    for (int j = 0; j < 8; j++) tb[o * 36 + kkb + j] = fmaxf(fmaf(sc, t[j], sh), 0.f);
  }
  __syncthreads();
  float acc2[8];
  {
    float bv = b1[o];
#pragma unroll
    for (int j = 0; j < 8; j++) acc2[j] = bv;
  }
  for (int c = 0; c < 64; c++) {
    float w = Wt[c * 65 + o];
    const float4 ta = *(const float4*)(tb + c * 36 + kkb);
    const float4 ta2 = *(const float4*)(tb + c * 36 + kkb + 4);
    acc2[0] += w * ta.x; acc2[1] += w * ta.y; acc2[2] += w * ta.z; acc2[3] += w * ta.w;
    acc2[4] += w * ta2.x; acc2[5] += w * ta2.y; acc2[6] += w * ta2.z; acc2[7] += w * ta2.w;
  }
  {
    float4* up = (float4*)(ucache + ((size_t)bs * 64 + o) * 32 + kkb);
    up[0] = make_float4(acc2[0], acc2[1], acc2[2], acc2[3]);
    up[1] = make_float4(acc2[4], acc2[5], acc2[6], acc2[7]);
  }
  float s8 = 0.f, q8 = 0.f;
#pragma unroll
  for (int j = 0; j < 8; j++) { s8 += acc2[j]; q8 += acc2[j] * acc2[j]; }
  part[(tid >> 6) * 64 + o] = s8;
  part[256 + (tid >> 6) * 64 + o] = q8;
  __syncthreads();
  if (tid < 64) {
    float ss = 0.f, qq = 0.f;
    for (int g = 0; g < 4; g++) { ss += part[g * 64 + tid]; qq += part[256 + g * 64 + tid]; }
    bnpart[(size_t)bs * 128 + tid] = ss;
    bnpart[(size_t)bs * 128 + 64 + tid] = qq;
  }
}

// MLP stage 2: u = bn+relu(ucache); conv2; residual with bn+relu(tcache); max.
__global__ __launch_bounds__(256, 3) void mlp2c(
    const float* __restrict__ tcache, const float* __restrict__ ucache,
    const float* __restrict__ bn_tr, const float* __restrict__ bn_1,
    const float* __restrict__ w2, const float* __restrict__ b2,
    float* __restrict__ out1) {
  __shared__ __align__(16) float pool[6976];
  float* Wt = pool;
  float* ub = pool + 4160;
  float* part = pool + 4160 + 2304;
  const int bs = blockIdx.x, tid = threadIdx.x;
  const int b = bs >> 10, s = bs & 1023;
  const int o = tid & 63, kkb = (tid >> 6) * 8;
  for (int e = tid; e < 64 * 64; e += 256) {
    int oo = e >> 6, c = e & 63;
    Wt[c * 65 + oo] = w2[e];
  }
  {
    const float4* up = (const float4*)(ucache + ((size_t)bs * 64 + o) * 32 + kkb);
    float4 a = up[0], b4 = up[1];
    float u[8] = {a.x, a.y, a.z, a.w, b4.x, b4.y, b4.z, b4.w};
    float sc = bn_1[o], sh = bn_1[64 + o];
#pragma unroll
    for (int j = 0; j < 8; j++) ub[o * 36 + kkb + j] = fmaxf(fmaf(sc, u[j], sh), 0.f);
  }
  __syncthreads();
  float acc3[8];
  {
    float bv = b2[o];
#pragma unroll
    for (int j = 0; j < 8; j++) acc3[j] = bv;
  }
  for (int c = 0; c < 64; c++) {
    float w = Wt[c * 65 + o];
    const float4 ua = *(const float4*)(ub + c * 36 + kkb);
    const float4 ua2 = *(const float4*)(ub + c * 36 + kkb + 4);
    acc3[0] += w * ua.x; acc3[1] += w * ua.y; acc3[2] += w * ua.z; acc3[3] += w * ua.w;
    acc3[4] += w * ua2.x; acc3[5] += w * ua2.y; acc3[6] += w * ua2.z; acc3[7] += w * ua2.w;
  }
  float tv[8];
  {
    const float4* tp = (const float4*)(tcache + ((size_t)bs * 64 + o) * 32 + kkb);
    float4 a = tp[0], b4 = tp[1];
    float t[8] = {a.x, a.y, a.z, a.w, b4.x, b4.y, b4.z, b4.w};
    float sc = bn_tr[o], sh = bn_tr[64 + o];
#pragma unroll
    for (int j = 0; j < 8; j++) tv[j] = fmaxf(fmaf(sc, t[j], sh), 0.f);
  }
  float m = 0.f;
#pragma unroll
  for (int j = 0; j < 8; j++) m = fmaxf(m, fmaxf(acc3[j] + tv[j], 0.f));
  part[(tid >> 6) * 64 + o] = m;
  __syncthreads();
  if (tid < 64) {
    float mm = part[tid];
    for (int g = 1; g < 4; g++) mm = fmaxf(mm, part[g * 64 + tid]);
    out1[((size_t)b * 64 + tid) * S_ + s] = mm;
  }
}

// ---------------------------------------------------------------------------
extern "C" void kernel_launch(void* const* d_in, const int* in_sizes, int n_in,
                              void* d_out, int out_size, void* d_ws, size_t ws_size,
                              hipStream_t stream) {
  const float* xyz = (const float*)d_in[0];
  const float* feature = (const float*)d_in[1];
  const float* alpha = (const float*)d_in[2];
  const float* beta = (const float*)d_in[3];
  const float* w_tr = (const float*)d_in[4];
  const float* b_tr = (const float*)d_in[5];
  const float* g_tr = (const float*)d_in[6];
  const float* be_tr = (const float*)d_in[7];
  const float* w1 = (const float*)d_in[8];
  const float* b1 = (const float*)d_in[9];
  const float* g1 = (const float*)d_in[10];
  const float* be1 = (const float*)d_in[11];
  const float* w2 = (const float*)d_in[12];
  const float* b2 = (const float*)d_in[13];

  char* ws = (char*)d_ws;
  int* fps_i = (int*)(ws);                      // 32768 B
  float* nxyz = (float*)(ws + 32768);           // 98304 B
  float* nfeat = (float*)(ws + 131072);         // 2097152 B
  int* knn = (int*)(ws + 2228224);              // 1048576 B
  float* stdpart = (float*)(ws + 3276800);      // 4096 B (fallback)
  float* invstd = (float*)(ws + 3280896);       // 64 B
  float* bn_tr = (float*)(ws + 3280960);        // 512 B
  float* bn_1 = (float*)(ws + 3281472);         // 512 B
  float* bnpart = (float*)(ws + 3281984);       // 4194304 B -> end 7476288
  // cache-path extras
  float* featT = (float*)(ws + 7476288);        // 8388608 B
  float* dcache = (float*)(ws + 15864896);      // 71303168 B
  float* tcache = (float*)(ws + 87168064);      // 67108864 B
  float* ucache = (float*)(ws + 154276928);     // 67108864 B
  float* stdpart_c = (float*)(ws + 221385792);  // 8192 B -> total 221393984

  float* out0 = (float*)d_out;
  float* out1 = out0 + B_ * 3 * S_;

  const bool big = (ws_size >= 221393984ull);

  fps_kernel<<<B_, 512, 0, stream>>>(xyz, fps_i, nxyz, out0);

  if (big) {
    transpose_feat<<<8 * 64, 256, 0, stream>>>(feature, featT);
    knn_kernel<<<B_ * S_, 256, 0, stream>>>(xyz, nxyz, knn);
    gather_nf_c<<<(B_ * S_ * D_) / 256, 256, 0, stream>>>(featT, fps_i, nfeat);
    prep_kernel<<<1024, 256, 0, stream>>>(featT, xyz, nxyz, nfeat, knn, dcache, stdpart_c);
    std_final_c<<<1, 64, 0, stream>>>(stdpart_c, invstd);
    mlp0c<<<B_ * S_, 256, 0, stream>>>(dcache, nfeat, invstd, alpha, beta, w_tr, b_tr,
                                       bnpart, tcache);
    bn_finalize<<<64, 256, 0, stream>>>(bnpart, g_tr, be_tr, bn_tr);
    mlp1c<<<B_ * S_, 256, 0, stream>>>(tcache, bn_tr, w1, b1, bnpart, ucache);
    bn_finalize<<<64, 256, 0, stream>>>(bnpart, g1, be1, bn_1);
    mlp2c<<<B_ * S_, 256, 0, stream>>>(tcache, ucache, bn_tr, bn_1, w2, b2, out1);
  } else {
    gather_nf<<<(B_ * S_ * D_) / 256, 256, 0, stream>>>(feature, fps_i, nfeat);
    knn_kernel<<<B_ * S_, 256, 0, stream>>>(xyz, nxyz, knn);
    std_partial<<<B_ * 64, 256, 0, stream>>>(feature, xyz, nxyz, nfeat, knn, stdpart);
    std_final<<<1, 64, 0, stream>>>(stdpart, invstd);
    mlp_kernel<0><<<B_ * S_, 256, 0, stream>>>(feature, xyz, nxyz, nfeat, knn, invstd,
                                               alpha, beta, w_tr, b_tr, w1, b1, w2, b2,
                                               bn_tr, bn_1, bnpart, out1);
    bn_finalize<<<64, 256, 0, stream>>>(bnpart, g_tr, be_tr, bn_tr);
    mlp_kernel<1><<<B_ * S_, 256, 0, stream>>>(feature, xyz, nxyz, nfeat, knn, invstd,
                                               alpha, beta, w_tr, b_tr, w1, b1, w2, b2,
                                               bn_tr, bn_1, bnpart, out1);
    bn_finalize<<<64, 256, 0, stream>>>(bnpart, g1, be1, bn_1);
    mlp_kernel<2><<<B_ * S_, 256, 0, stream>>>(feature, xyz, nxyz, nfeat, knn, invstd,
                                               alpha, beta, w_tr, b_tr, w1, b1, w2, b2,
                                               bn_tr, bn_1, bnpart, out1);
  }
}

// Round 8
// 1164.729 us; speedup vs baseline: 2.1447x; 1.0271x over previous
//
#include <hip/hip_runtime.h>
#include <cfloat>
#include <math.h>

#define B_ 8
#define N_ 4096
#define D_ 64
#define S_ 1024
#define K_ 32
#define CIN_ 131  // 2*D + 3

// Move a u64 across lanes with a constant DPP control (2x 32-bit update_dpp).
template <int CTRL>
__device__ __forceinline__ unsigned long long dpp_u64(unsigned long long k) {
  int lo = (int)(unsigned int)k, hi = (int)(unsigned int)(k >> 32);
  lo = __builtin_amdgcn_update_dpp(lo, lo, CTRL, 0xf, 0xf, false);
  hi = __builtin_amdgcn_update_dpp(hi, hi, CTRL, 0xf, 0xf, false);
  return ((unsigned long long)(unsigned int)hi << 32) | (unsigned int)lo;
}

// Wave(64)-wide float max via DPP (VALU pipe). Result broadcast via readlane 63.
__device__ __forceinline__ float wave_max_f32_dpp(float v) {
  int x = __float_as_int(v);
#define STEP(ctrl)                                                        \
  {                                                                       \
    int t = __builtin_amdgcn_update_dpp(x, x, ctrl, 0xf, 0xf, false);     \
    v = fmaxf(v, __int_as_float(t));                                      \
    x = __float_as_int(v);                                                \
  }
  STEP(0x111)
  STEP(0x112)
  STEP(0x114)
  STEP(0x118)
  STEP(0x142)
  STEP(0x143)
#undef STEP
  return __int_as_float(__builtin_amdgcn_readlane(x, 63));
}

// ---------------------------------------------------------------------------
// FPS: blocks 0..7 do FPS (256 threads, thread t owns contiguous [16t,16t+16)
// -> 4 waves: halves the per-step reduce/merge overhead issue vs 512 thr while
// dist-update issue is unchanged and 16-pt ILP hides VALU latency).
// Blocks 8..519 transpose feature [b][c][n] -> featT [b][n][c] (independent
// work fused into this dispatch; reuses sp[] LDS as the 64x65 tile).
// Per FPS step: local argmax -> DPP wave max + ballot resolve -> lane-0
// writes packed u64 winner -> ONE barrier -> read keyp[lane&3], 2 DPP-step
// merge -> next centroid from LDS. No global ops in the loop.
// ---------------------------------------------------------------------------
__global__ __launch_bounds__(256) void fps_kernel(const float* __restrict__ xyz,
                                                  int* __restrict__ fps_idx,
                                                  float* __restrict__ nxyz,
                                                  float* __restrict__ out0,
                                                  const float* __restrict__ feature,
                                                  float* __restrict__ featT) {
  const int tid = threadIdx.x;
  __shared__ __align__(16) float4 sp[N_];    // 64 KB coord mirror / transpose tile
  __shared__ int si[S_];
  __shared__ unsigned long long keyp[2][4];
  if (blockIdx.x >= 8) {
    // ---- fused transpose (validated r7 transpose_feat logic, 256 thr) ----
    const int blk = blockIdx.x - 8;
    const int b = blk >> 6, n0 = (blk & 63) * 64;
    float* tile = (float*)sp;  // 64*65 floats = 16.6 KB
#pragma unroll
    for (int i = 0; i < 16; i++) {
      int c = i * 4 + (tid >> 6), nl = tid & 63;
      tile[c * 65 + nl] = feature[((size_t)b * 64 + c) * N_ + n0 + nl];
    }
    __syncthreads();
#pragma unroll
    for (int i = 0; i < 16; i++) {
      int nl = i * 4 + (tid >> 6), c = tid & 63;
      featT[((size_t)b * N_ + n0 + nl) * 64 + c] = tile[c * 65 + nl];
    }
    return;
  }
  const int b = blockIdx.x;
  const float* xb = xyz + (size_t)b * 3 * N_;
  const float4* xv = (const float4*)xb;
  float px[16], py[16], pz[16], dist[16];
#pragma unroll
  for (int q = 0; q < 4; q++) {
    float4 X = xv[4 * tid + q];
    float4 Y = xv[1024 + 4 * tid + q];
    float4 Z = xv[2048 + 4 * tid + q];
    px[4 * q + 0] = X.x; px[4 * q + 1] = X.y; px[4 * q + 2] = X.z; px[4 * q + 3] = X.w;
    py[4 * q + 0] = Y.x; py[4 * q + 1] = Y.y; py[4 * q + 2] = Y.z; py[4 * q + 3] = Y.w;
    pz[4 * q + 0] = Z.x; pz[4 * q + 1] = Z.y; pz[4 * q + 2] = Z.z; pz[4 * q + 3] = Z.w;
  }
#pragma unroll
  for (int i = 0; i < 16; i++) {
    dist[i] = 1e10f;
    sp[16 * tid + i] = make_float4(px[i], py[i], pz[i], 0.f);
  }
  if (tid == 0) si[0] = 0;
  __syncthreads();
  float cx = sp[0].x, cy = sp[0].y, cz = sp[0].z;
  const int wav = tid >> 6, lane = tid & 63;
  for (int s = 1; s < S_; s++) {
    float best = -1.0f;
    int bi = 16 * tid;
#pragma unroll
    for (int i = 0; i < 16; i++) {
      // no-FMA arithmetic, identical op order to validated rounds
      float dx = __fsub_rn(px[i], cx);
      float dy = __fsub_rn(py[i], cy);
      float dz = __fsub_rn(pz[i], cz);
      float d = __fadd_rn(__fadd_rn(__fmul_rn(dx, dx), __fmul_rn(dy, dy)), __fmul_rn(dz, dz));
      dist[i] = fminf(dist[i], d);
      if (dist[i] > best) { best = dist[i]; bi = 16 * tid + i; }  // strict >: smallest idx
    }
    float wmax = wave_max_f32_dpp(best);
    unsigned long long m = __ballot(best == wmax);
    int l = __ffsll(m) - 1;
    int widx = __builtin_amdgcn_readlane(bi, l);
    if (lane == 0)
      keyp[s & 1][wav] =
          ((unsigned long long)(unsigned int)__float_as_int(wmax) << 32) |
          (unsigned int)(4095 - widx);
    __syncthreads();
    // merge 4 per-wave winners: 1 LDS read + 2 DPP steps (period-4 in quads)
    unsigned long long k = keyp[s & 1][lane & 3];
    unsigned long long t;
    t = dpp_u64<0xB1>(k); if (t > k) k = t;  // quad_perm xor 1
    t = dpp_u64<0x4E>(k); if (t > k) k = t;  // quad_perm xor 2
    int bix = 4095 - (int)(k & 0xfffull);
    if (tid == 0) si[s] = bix;
    float4 c = sp[bix];
    cx = c.x; cy = c.y; cz = c.z;
  }
  __syncthreads();
  for (int e = tid; e < S_; e += 256) {
    int n = si[e];
    fps_idx[b * S_ + e] = n;
    float4 c = sp[n];
    nxyz[(size_t)(b * S_ + e) * 3 + 0] = c.x;
    nxyz[(size_t)(b * S_ + e) * 3 + 1] = c.y;
    nxyz[(size_t)(b * S_ + e) * 3 + 2] = c.z;
    out0[(size_t)b * 3 * S_ + e] = c.x;
    out0[(size_t)b * 3 * S_ + S_ + e] = c.y;
    out0[(size_t)b * 3 * S_ + 2 * S_ + e] = c.z;
  }
}

// ---------------------------------------------------------------------------
// kNN (validated r4/r7 inner logic — unchanged). Blocks >= 8192 perform the
// fused anchor-feature gather from featT (validated gather_nf_c logic).
// ---------------------------------------------------------------------------
__global__ __launch_bounds__(256) void knn_kernel(const float* __restrict__ xyz,
                                                  const float* __restrict__ nxyz,
                                                  int* __restrict__ knn,
                                                  const float* __restrict__ featT,
                                                  const int* __restrict__ fps_i,
                                                  float* __restrict__ nfeat) {
  const int bs = blockIdx.x, tid = threadIdx.x;
  if (bs >= 8192) {
    int e = (bs - 8192) * 256 + tid;  // < B*S*D
    int bsx = e >> 6, c = e & 63;
    int bq = bsx >> 10;
    int n = fps_i[bsx];
    nfeat[e] = featT[((size_t)bq * N_ + n) * 64 + c];
    return;
  }
  const int b = bs >> 10;
  const float* xb = xyz + (size_t)b * 3 * N_;
  const float cx = nxyz[(size_t)bs * 3], cy = nxyz[(size_t)bs * 3 + 1], cz = nxyz[(size_t)bs * 3 + 2];
  const float cn = __fadd_rn(__fadd_rn(__fmul_rn(cx, cx), __fmul_rn(cy, cy)), __fmul_rn(cz, cz));
  float d[16];
#pragma unroll
  for (int i = 0; i < 16; i++) {
    int n = i * 256 + tid;
    float px = xb[n], py = xb[N_ + n], pz = xb[2 * N_ + n];
    float pn = __fadd_rn(__fadd_rn(__fmul_rn(px, px), __fmul_rn(py, py)), __fmul_rn(pz, pz));
    float dot = __fadd_rn(__fadd_rn(__fmul_rn(cx, px), __fmul_rn(cy, py)), __fmul_rn(cz, pz));
    d[i] = __fsub_rn(__fadd_rn(cn, pn), __fmul_rn(2.0f, dot));
  }
  float mv = FLT_MAX;
  int mi = tid;
#pragma unroll
  for (int i = 0; i < 16; i++)
    if (d[i] < mv) { mv = d[i]; mi = i * 256 + tid; }
  __shared__ unsigned long long keyp[2][4];
  __shared__ int skk[K_];
  const int wav = tid >> 6, lane = tid & 63;
  for (int j = 0; j < K_; j++) {
    unsigned int u = __float_as_uint(mv);
    u ^= ((unsigned int)((int)u >> 31) | 0x80000000u);
    unsigned long long key = ((unsigned long long)u << 32) | (unsigned int)mi;
#pragma unroll
    for (int off = 32; off >= 1; off >>= 1) {
      unsigned long long ok = __shfl_xor(key, off);
      if (ok < key) key = ok;
    }
    if (lane == 0) keyp[j & 1][wav] = key;
    __syncthreads();
    unsigned long long kmin = keyp[j & 1][0];
#pragma unroll
    for (int w = 1; w < 4; w++) {
      unsigned long long k2 = keyp[j & 1][w];
      if (k2 < kmin) kmin = k2;
    }
    int g = (int)(kmin & 0xffffffffull);
    if (tid == 0) skk[j] = g;
    if ((g & 255) == tid) {
      int sl = g >> 8;
#pragma unroll
      for (int i = 0; i < 16; i++)
        if (i == sl) d[i] = FLT_MAX;
      mv = FLT_MAX; mi = tid;
#pragma unroll
      for (int i = 0; i < 16; i++)
        if (d[i] < mv) { mv = d[i]; mi = i * 256 + tid; }
    }
  }
  __syncthreads();
  if (tid < K_) knn[(size_t)bs * K_ + tid] = skk[tid];
}

// ===========================================================================
// ============ FALLBACK (r6) kernels — used when ws is small ================
// ===========================================================================
__global__ __launch_bounds__(256) void gather_nf(const float* __restrict__ feature,
                                                 const int* __restrict__ fps_i,
                                                 float* __restrict__ nfeat) {
  int e = blockIdx.x * 256 + threadIdx.x;
  int b = e >> 16, rem = e & 65535;
  int s = rem >> 6, c = rem & 63;
  int n = fps_i[b * S_ + s];
  nfeat[e] = feature[((size_t)b * 64 + c) * N_ + n];
}

__global__ __launch_bounds__(256) void std_partial(const float* __restrict__ feature,
                                                   const float* __restrict__ xyz,
                                                   const float* __restrict__ nxyz,
                                                   const float* __restrict__ nfeat,
                                                   const int* __restrict__ knn,
                                                   float* __restrict__ outp) {
  const int blk = blockIdx.x, tid = threadIdx.x;
  const int b = blk >> 6, chunk = blk & 63;
  float s = 0.f, q = 0.f;
  for (int e = tid; e < 16 * K_ * 67; e += 256) {
    int so = e / (K_ * 67);
    int rem = e - so * (K_ * 67);
    int kk = rem / 67;
    int c = rem - kk * 67;
    int bs = b * S_ + chunk * 16 + so;
    int n = knn[(size_t)bs * K_ + kk];
    float raw = (c < 64) ? feature[((size_t)b * 64 + c) * N_ + n]
                         : xyz[((size_t)b * 3 + (c - 64)) * N_ + n];
    float anc = (c < 64) ? nfeat[(size_t)bs * 64 + c]
                         : nxyz[(size_t)bs * 3 + (c - 64)];
    float dd = raw - anc;
    s += dd; q += dd * dd;
  }
#pragma unroll
  for (int off = 32; off >= 1; off >>= 1) { s += __shfl_xor(s, off); q += __shfl_xor(q, off); }
  __shared__ float rs[4], rq[4];
  if ((tid & 63) == 0) { rs[tid >> 6] = s; rq[tid >> 6] = q; }
  __syncthreads();
  if (tid == 0) {
    outp[blk * 2] = rs[0] + rs[1] + rs[2] + rs[3];
    outp[blk * 2 + 1] = rq[0] + rq[1] + rq[2] + rq[3];
  }
}

__global__ void std_final(const float* __restrict__ part, float* __restrict__ invstd) {
  int b = threadIdx.x;
  if (b < B_) {
    double s = 0.0, q = 0.0;
    for (int i = 0; i < 64; i++) {
      s += (double)part[(b * 64 + i) * 2];
      q += (double)part[(b * 64 + i) * 2 + 1];
    }
    const double n = (double)(S_ * K_ * 67);
    double var = (q - s * s / n) / (n - 1.0);
    invstd[b] = (float)(1.0 / (sqrt(var) + 1e-5));
  }
}

template <int MODE>
__global__ __launch_bounds__(256, 2) void mlp_kernel(
    const float* __restrict__ feature, const float* __restrict__ xyz,
    const float* __restrict__ nxyz, const float* __restrict__ nfeat,
    const int* __restrict__ knn, const float* __restrict__ invstd,
    const float* __restrict__ alpha, const float* __restrict__ beta,
    const float* __restrict__ w_tr, const float* __restrict__ b_tr,
    const float* __restrict__ w1, const float* __restrict__ b1,
    const float* __restrict__ w2, const float* __restrict__ b2,
    const float* __restrict__ bn_tr, const float* __restrict__ bn_1,
    float* __restrict__ bnpart, float* __restrict__ out1) {
  __shared__ __align__(16) float pool[15556];
  float* Wt = pool;
  float* xin = pool + 8516;
  float* ub = xin;
  float* tb = pool + 8516 + 4192;
  float* part = pool + 8516 + 4192 + 2304;
  int* sknn = (int*)(part + 512);
  const int bs = blockIdx.x, tid = threadIdx.x;
  const int b = bs >> 10, s = bs & 1023;
  if (tid < K_) sknn[tid] = knn[(size_t)bs * K_ + tid];
  for (int e = tid; e < 64 * 131; e += 256) {
    int o = e / 131, c = e - o * 131;
    Wt[c * 65 + o] = w_tr[e];
  }
  __syncthreads();
  const float inv = invstd[b];
  for (int e = tid; e < CIN_ * K_; e += 256) {
    int c = e >> 5, kk = e & 31;
    float v;
    if (c < 67) {
      int n = sknn[kk];
      float raw = (c < 64) ? feature[((size_t)b * 64 + c) * N_ + n]
                           : xyz[((size_t)b * 3 + (c - 64)) * N_ + n];
      float anc = (c < 64) ? nfeat[(size_t)bs * 64 + c]
                           : nxyz[(size_t)bs * 3 + (c - 64)];
      v = alpha[c] * ((raw - anc) * inv) + beta[c];
    } else {
      v = nfeat[(size_t)bs * 64 + (c - 67)];
    }
    xin[e] = v;
  }
  __syncthreads();
  const int o = tid & 63, kkb = (tid >> 6) * 8;
  float acc[8];
  {
    float bv = b_tr[o];
#pragma unroll
    for (int j = 0; j < 8; j++) acc[j] = bv;
  }
  for (int c = 0; c < CIN_; c++) {
    float w = Wt[c * 65 + o];
    const float4 xa = *(const float4*)(xin + c * 32 + kkb);
    const float4 xb4 = *(const float4*)(xin + c * 32 + kkb + 4);
    acc[0] += w * xa.x; acc[1] += w * xa.y; acc[2] += w * xa.z; acc[3] += w * xa.w;
    acc[4] += w * xb4.x; acc[5] += w * xb4.y; acc[6] += w * xb4.z; acc[7] += w * xb4.w;
  }
  if (MODE == 0) {
    float s8 = 0.f, q8 = 0.f;
#pragma unroll
    for (int j = 0; j < 8; j++) { s8 += acc[j]; q8 += acc[j] * acc[j]; }
    part[(tid >> 6) * 64 + o] = s8;
    part[256 + (tid >> 6) * 64 + o] = q8;
    __syncthreads();
    if (tid < 64) {
      float ss = 0.f, qq = 0.f;
      for (int g = 0; g < 4; g++) { ss += part[g * 64 + tid]; qq += part[256 + g * 64 + tid]; }
      bnpart[(size_t)bs * 128 + tid] = ss;
      bnpart[(size_t)bs * 128 + 64 + tid] = qq;
    }
    return;
  }
  float tv[8];
  {
    float sc = bn_tr[o], sh = bn_tr[64 + o];
#pragma unroll
    for (int j = 0; j < 8; j++) {
      tv[j] = fmaxf(fmaf(sc, acc[j], sh), 0.f);
      tb[o * 36 + kkb + j] = tv[j];
    }
  }
  __syncthreads();
  for (int e = tid; e < 64 * 64; e += 256) {
    int oo = e >> 6, c = e & 63;
    Wt[c * 65 + oo] = w1[e];
  }
  __syncthreads();
  float acc2[8];
  {
    float bv = b1[o];
#pragma unroll
    for (int j = 0; j < 8; j++) acc2[j] = bv;
  }
  for (int c = 0; c < 64; c++) {
    float w = Wt[c * 65 + o];
    const float4 ta = *(const float4*)(tb + c * 36 + kkb);
    const float4 ta2 = *(const float4*)(tb + c * 36 + kkb + 4);
    acc2[0] += w * ta.x; acc2[1] += w * ta.y; acc2[2] += w * ta.z; acc2[3] += w * ta.w;
    acc2[4] += w * ta2.x; acc2[5] += w * ta2.y; acc2[6] += w * ta2.z; acc2[7] += w * ta2.w;
  }
  if (MODE == 1) {
    float s8 = 0.f, q8 = 0.f;
#pragma unroll
    for (int j = 0; j < 8; j++) { s8 += acc2[j]; q8 += acc2[j] * acc2[j]; }
    part[(tid >> 6) * 64 + o] = s8;
    part[256 + (tid >> 6) * 64 + o] = q8;
    __syncthreads();
    if (tid < 64) {
      float ss = 0.f, qq = 0.f;
      for (int g = 0; g < 4; g++) { ss += part[g * 64 + tid]; qq += part[256 + g * 64 + tid]; }
      bnpart[(size_t)bs * 128 + tid] = ss;
      bnpart[(size_t)bs * 128 + 64 + tid] = qq;
    }
    return;
  }
  {
    float sc = bn_1[o], sh = bn_1[64 + o];
#pragma unroll
    for (int j = 0; j < 8; j++) ub[o * 36 + kkb + j] = fmaxf(fmaf(sc, acc2[j], sh), 0.f);
  }
  __syncthreads();
  for (int e = tid; e < 64 * 64; e += 256) {
    int oo = e >> 6, c = e & 63;
    Wt[c * 65 + oo] = w2[e];
  }
  __syncthreads();
  float acc3[8];
  {
    float bv = b2[o];
#pragma unroll
    for (int j = 0; j < 8; j++) acc3[j] = bv;
  }
  for (int c = 0; c < 64; c++) {
    float w = Wt[c * 65 + o];
    const float4 ua = *(const float4*)(ub + c * 36 + kkb);
    const float4 ua2 = *(const float4*)(ub + c * 36 + kkb + 4);
    acc3[0] += w * ua.x; acc3[1] += w * ua.y; acc3[2] += w * ua.z; acc3[3] += w * ua.w;
    acc3[4] += w * ua2.x; acc3[5] += w * ua2.y; acc3[6] += w * ua2.z; acc3[7] += w * ua2.w;
  }
  float m = 0.f;
#pragma unroll
  for (int j = 0; j < 8; j++) m = fmaxf(m, fmaxf(acc3[j] + tv[j], 0.f));
  part[(tid >> 6) * 64 + o] = m;
  __syncthreads();
  if (tid < 64) {
    float mm = part[tid];
    for (int g = 1; g < 4; g++) mm = fmaxf(mm, part[g * 64 + tid]);
    out1[((size_t)b * 64 + tid) * S_ + s] = mm;
  }
}

// ---------------------------------------------------------------------------
// BN finalize (shared by both paths).
// ---------------------------------------------------------------------------
__global__ __launch_bounds__(256) void bn_finalize(const float* __restrict__ part,
                                                   const float* __restrict__ g,
                                                   const float* __restrict__ be,
                                                   float* __restrict__ bnout) {
  const int ch = blockIdx.x, tid = threadIdx.x;
  double s = 0.0, q = 0.0;
  for (int i = tid; i < B_ * S_; i += 256) {
    s += (double)part[(size_t)i * 128 + ch];
    q += (double)part[(size_t)i * 128 + 64 + ch];
  }
#pragma unroll
  for (int off = 32; off >= 1; off >>= 1) { s += __shfl_xor(s, off); q += __shfl_xor(q, off); }
  __shared__ double ls[4], lq[4];
  if ((tid & 63) == 0) { ls[tid >> 6] = s; lq[tid >> 6] = q; }
  __syncthreads();
  if (tid == 0) {
    double Ssum = ls[0] + ls[1] + ls[2] + ls[3];
    double Qsum = lq[0] + lq[1] + lq[2] + lq[3];
    const double n = (double)(B_ * S_ * K_);
    double mu = Ssum / n;
    double var = Qsum / n - mu * mu;
    double sc = (double)g[ch] / sqrt(var + 1e-5);
    bnout[ch] = (float)sc;
    bnout[64 + ch] = (float)((double)be[ch] - mu * sc);
  }
}

// ===========================================================================
// ================== CACHE-PATH kernels (large workspace) ===================
// ===========================================================================

// Fused diff computation + std partials. 1024 blocks x 8 groups.
__global__ __launch_bounds__(256) void prep_kernel(const float* __restrict__ featT,
                                                   const float* __restrict__ xyz,
                                                   const float* __restrict__ nxyz,
                                                   const float* __restrict__ nfeat,
                                                   const int* __restrict__ knn,
                                                   float* __restrict__ dcache,
                                                   float* __restrict__ outp) {
  const int blk = blockIdx.x, tid = threadIdx.x;
  __shared__ int sk[32];
  float s = 0.f, q = 0.f;
  const int c = tid & 63, qd = tid >> 6;
  for (int g = 0; g < 8; g++) {
    const int bs = blk * 8 + g, b = bs >> 10;
    if (tid < 32) sk[tid] = knn[(size_t)bs * K_ + tid];
    __syncthreads();
    float anc = nfeat[(size_t)bs * 64 + c];
#pragma unroll
    for (int it = 0; it < 8; it++) {
      int kk = it * 4 + qd;
      int n = sk[kk];
      float dd = featT[((size_t)b * N_ + n) * 64 + c] - anc;
      s += dd; q += dd * dd;
      dcache[((size_t)bs * 32 + kk) * 68 + c] = dd;
    }
    if (tid < 96) {
      int c3 = tid >> 5, kk = tid & 31;
      int n = sk[kk];
      float dd = xyz[((size_t)b * 3 + c3) * N_ + n] - nxyz[(size_t)bs * 3 + c3];
      s += dd; q += dd * dd;
      dcache[((size_t)bs * 32 + kk) * 68 + 64 + c3] = dd;
    }
    __syncthreads();
  }
#pragma unroll
  for (int off = 32; off >= 1; off >>= 1) { s += __shfl_xor(s, off); q += __shfl_xor(q, off); }
  __shared__ float rs[4], rq[4];
  if ((tid & 63) == 0) { rs[tid >> 6] = s; rq[tid >> 6] = q; }
  __syncthreads();
  if (tid == 0) {
    outp[blk * 2] = rs[0] + rs[1] + rs[2] + rs[3];
    outp[blk * 2 + 1] = rq[0] + rq[1] + rq[2] + rq[3];
  }
}

__global__ void std_final_c(const float* __restrict__ part, float* __restrict__ invstd) {
  int b = threadIdx.x;
  if (b < B_) {
    double s = 0.0, q = 0.0;
    for (int i = 0; i < 128; i++) {
      s += (double)part[(b * 128 + i) * 2];
      q += (double)part[(b * 128 + i) * 2 + 1];
    }
    const double n = (double)(S_ * K_ * 67);
    double var = (q - s * s / n) / (n - 1.0);
    invstd[b] = (float)(1.0 / (sqrt(var) + 1e-5));
  }
}

// MLP stage 0: xin from dcache (coalesced), conv_tr, stats + tcache store.
__global__ __launch_bounds__(256, 2) void mlp0c(
    const float* __restrict__ dcache, const float* __restrict__ nfeat,
    const float* __restrict__ invstd,
    const float* __restrict__ alpha, const float* __restrict__ beta,
    const float* __restrict__ w_tr, const float* __restrict__ b_tr,
    float* __restrict__ bnpart, float* __restrict__ tcache) {
  __shared__ __align__(16) float pool[13220];
  float* Wt = pool;
  float* xin = pool + 8516;
  float* part = pool + 8516 + 4192;
  const int bs = blockIdx.x, tid = threadIdx.x;
  const int b = bs >> 10;
  for (int e = tid; e < 64 * 131; e += 256) {
    int o = e / 131, c = e - o * 131;
    Wt[c * 65 + o] = w_tr[e];
  }
  const float inv = invstd[b];
  {
    const int c = tid & 63, qd = tid >> 6;
    float al = alpha[c], bev = beta[c];
#pragma unroll
    for (int it = 0; it < 8; it++) {
      int kk = it * 4 + qd;
      xin[c * 32 + kk] = al * (dcache[((size_t)bs * 32 + kk) * 68 + c] * inv) + bev;
    }
    if (tid < 96) {
      int c3 = 64 + (tid >> 5), kk = tid & 31;
      xin[c3 * 32 + kk] =
          alpha[c3] * (dcache[((size_t)bs * 32 + kk) * 68 + c3] * inv) + beta[c3];
    }
    for (int e = tid; e < 2048; e += 256) {
      int cc = 67 + (e >> 5), kk = e & 31;
      xin[cc * 32 + kk] = nfeat[(size_t)bs * 64 + (e >> 5)];
    }
  }
  __syncthreads();
  const int o = tid & 63, kkb = (tid >> 6) * 8;
  float acc[8];
  {
    float bv = b_tr[o];
#pragma unroll
    for (int j = 0; j < 8; j++) acc[j] = bv;
  }
  for (int c = 0; c < CIN_; c++) {
    float w = Wt[c * 65 + o];
    const float4 xa = *(const float4*)(xin + c * 32 + kkb);
    const float4 xb4 = *(const float4*)(xin + c * 32 + kkb + 4);
    acc[0] += w * xa.x; acc[1] += w * xa.y; acc[2] += w * xa.z; acc[3] += w * xa.w;
    acc[4] += w * xb4.x; acc[5] += w * xb4.y; acc[6] += w * xb4.z; acc[7] += w * xb4.w;
  }
  {
    float4* tp = (float4*)(tcache + ((size_t)bs * 64 + o) * 32 + kkb);
    tp[0] = make_float4(acc[0], acc[1], acc[2], acc[3]);
    tp[1] = make_float4(acc[4], acc[5], acc[6], acc[7]);
  }
  float s8 = 0.f, q8 = 0.f;
#pragma unroll
  for (int j = 0; j < 8; j++) { s8 += acc[j]; q8 += acc[j] * acc[j]; }
  part[(tid >> 6) * 64 + o] = s8;
  part[256 + (tid >> 6) * 64 + o] = q8;
  __syncthreads();
  if (tid < 64) {
    float ss = 0.f, qq = 0.f;
    for (int g = 0; g < 4; g++) { ss += part[g * 64 + tid]; qq += part[256 + g * 64 + tid]; }
    bnpart[(size_t)bs * 128 + tid] = ss;
    bnpart[(size_t)bs * 128 + 64 + tid] = qq;
  }
}

// MLP stage 1: t = bn+relu(tcache); conv1; stats + ucache store.
__global__ __launch_bounds__(256, 3) void mlp1c(
    const float* __restrict__ tcache, const float* __restrict__ bn_tr,
    const float* __restrict__ w1, const float* __restrict__ b1,
    float* __restrict__ bnpart, float* __restrict__ ucache) {
  __shared__ __align__(16) float pool[6976];
  float* Wt = pool;
  float* tb = pool + 4160;
  float* part = pool + 4160 + 2304;
  const int bs = blockIdx.x, tid = threadIdx.x;
  const int o = tid & 63, kkb = (tid >> 6) * 8;
  for (int e = tid; e < 64 * 64; e += 256) {
    int oo = e >> 6, c = e & 63;
    Wt[c * 65 + oo] = w1[e];
  }
  float t[8];
  {
    const float4* tp = (const float4*)(tcache + ((size_t)bs * 64 + o) * 32 + kkb);
    float4 a = tp[0], b4 = tp[1];
    t[0] = a.x; t[1] = a.y; t[2] = a.z; t[3] = a.w;
    t[4] = b4.x; t[5] = b4.y; t[6] = b4.z; t[7] = b4.w;
  }
  {
    float sc = bn_tr[o], sh = bn_tr[64 + o];
#pragma unroll
    for (int j = 0; j < 8; j++) tb[o * 36 + kkb + j] = fmaxf(fmaf(sc, t[j], sh), 0.f);
  }
  __syncthreads();
  float acc2[8];
  {
    float bv = b1[o];
#pragma unroll
    for (int j = 0; j < 8; j++) acc2[j] = bv;
  }
  for (int c = 0; c < 64; c++) {
    float w = Wt[c * 65 + o];
    const float4 ta = *(const float4*)(tb + c * 36 + kkb);
    const float4 ta2 = *(const float4*)(tb + c * 36 + kkb + 4);
    acc2[0] += w * ta.x; acc2[1] += w * ta.y; acc2[2] += w * ta.z; acc2[3] += w * ta.w;
    acc2[4] += w * ta2.x; acc2[5] += w * ta2.y; acc2[6] += w * ta2.z; acc2[7] += w * ta2.w;
  }
  {
    float4* up = (float4*)(ucache + ((size_t)bs * 64 + o) * 32 + kkb);
    up[0] = make_float4(acc2[0], acc2[1], acc2[2], acc2[3]);
    up[1] = make_float4(acc2[4], acc2[5], acc2[6], acc2[7]);
  }
  float s8 = 0.f, q8 = 0.f;
#pragma unroll
  for (int j = 0; j < 8; j++) { s8 += acc2[j]; q8 += acc2[j] * acc2[j]; }
  part[(tid >> 6) * 64 + o] = s8;
  part[256 + (tid >> 6) * 64 + o] = q8;
  __syncthreads();
  if (tid < 64) {
    float ss = 0.f, qq = 0.f;
    for (int g = 0; g < 4; g++) { ss += part[g * 64 + tid]; qq += part[256 + g * 64 + tid]; }
    bnpart[(size_t)bs * 128 + tid] = ss;
    bnpart[(size_t)bs * 128 + 64 + tid] = qq;
  }
}

// MLP stage 2: u = bn+relu(ucache); conv2; residual with bn+relu(tcache); max.
__global__ __launch_bounds__(256, 3) void mlp2c(
    const float* __restrict__ tcache, const float* __restrict__ ucache,
    const float* __restrict__ bn_tr, const float* __restrict__ bn_1,
    const float* __restrict__ w2, const float* __restrict__ b2,
    float* __restrict__ out1) {
  __shared__ __align__(16) float pool[6976];
  float* Wt = pool;
  float* ub = pool + 4160;
  float* part = pool + 4160 + 2304;
  const int bs = blockIdx.x, tid = threadIdx.x;
  const int b = bs >> 10, s = bs & 1023;
  const int o = tid & 63, kkb = (tid >> 6) * 8;
  for (int e = tid; e < 64 * 64; e += 256) {
    int oo = e >> 6, c = e & 63;
    Wt[c * 65 + oo] = w2[e];
  }
  {
    const float4* up = (const float4*)(ucache + ((size_t)bs * 64 + o) * 32 + kkb);
    float4 a = up[0], b4 = up[1];
    float u[8] = {a.x, a.y, a.z, a.w, b4.x, b4.y, b4.z, b4.w};
    float sc = bn_1[o], sh = bn_1[64 + o];
#pragma unroll
    for (int j = 0; j < 8; j++) ub[o * 36 + kkb + j] = fmaxf(fmaf(sc, u[j], sh), 0.f);
  }
  __syncthreads();
  float acc3[8];
  {
    float bv = b2[o];
#pragma unroll
    for (int j = 0; j < 8; j++) acc3[j] = bv;
  }
  for (int c = 0; c < 64; c++) {
    float w = Wt[c * 65 + o];
    const float4 ua = *(const float4*)(ub + c * 36 + kkb);
    const float4 ua2 = *(const float4*)(ub + c * 36 + kkb + 4);
    acc3[0] += w * ua.x; acc3[1] += w * ua.y; acc3[2] += w * ua.z; acc3[3] += w * ua.w;
    acc3[4] += w * ua2.x; acc3[5] += w * ua2.y; acc3[6] += w * ua2.z; acc3[7] += w * ua2.w;
  }
  float tv[8];
  {
    const float4* tp = (const float4*)(tcache + ((size_t)bs * 64 + o) * 32 + kkb);
    float4 a = tp[0], b4 = tp[1];
    float t[8] = {a.x, a.y, a.z, a.w, b4.x, b4.y, b4.z, b4.w};
    float sc = bn_tr[o], sh = bn_tr[64 + o];
#pragma unroll
    for (int j = 0; j < 8; j++) tv[j] = fmaxf(fmaf(sc, t[j], sh), 0.f);
  }
  float m = 0.f;
#pragma unroll
  for (int j = 0; j < 8; j++) m = fmaxf(m, fmaxf(acc3[j] + tv[j], 0.f));
  part[(tid >> 6) * 64 + o] = m;
  __syncthreads();
  if (tid < 64) {
    float mm = part[tid];
    for (int g = 1; g < 4; g++) mm = fmaxf(mm, part[g * 64 + tid]);
    out1[((size_t)b * 64 + tid) * S_ + s] = mm;
  }
}

// ---------------------------------------------------------------------------
extern "C" void kernel_launch(void* const* d_in, const int* in_sizes, int n_in,
                              void* d_out, int out_size, void* d_ws, size_t ws_size,
                              hipStream_t stream) {
  const float* xyz = (const float*)d_in[0];
  const float* feature = (const float*)d_in[1];
  const float* alpha = (const float*)d_in[2];
  const float* beta = (const float*)d_in[3];
  const float* w_tr = (const float*)d_in[4];
  const float* b_tr = (const float*)d_in[5];
  const float* g_tr = (const float*)d_in[6];
  const float* be_tr = (const float*)d_in[7];
  const float* w1 = (const float*)d_in[8];
  const float* b1 = (const float*)d_in[9];
  const float* g1 = (const float*)d_in[10];
  const float* be1 = (const float*)d_in[11];
  const float* w2 = (const float*)d_in[12];
  const float* b2 = (const float*)d_in[13];

  char* ws = (char*)d_ws;
  int* fps_i = (int*)(ws);                      // 32768 B
  float* nxyz = (float*)(ws + 32768);           // 98304 B
  float* nfeat = (float*)(ws + 131072);         // 2097152 B
  int* knn = (int*)(ws + 2228224);              // 1048576 B
  float* stdpart = (float*)(ws + 3276800);      // 4096 B (fallback)
  float* invstd = (float*)(ws + 3280896);       // 64 B
  float* bn_tr = (float*)(ws + 3280960);        // 512 B
  float* bn_1 = (float*)(ws + 3281472);         // 512 B
  float* bnpart = (float*)(ws + 3281984);       // 4194304 B -> end 7476288
  float* featT = (float*)(ws + 7476288);        // 8388608 B
  float* dcache = (float*)(ws + 15864896);      // 71303168 B
  float* tcache = (float*)(ws + 87168064);      // 67108864 B
  float* ucache = (float*)(ws + 154276928);     // 67108864 B
  float* stdpart_c = (float*)(ws + 221385792);  // 8192 B -> total 221393984

  float* out0 = (float*)d_out;
  float* out1 = out0 + B_ * 3 * S_;

  const bool big = (ws_size >= 221393984ull);

  if (big) {
    // fps blocks 0..7 + 512 fused-transpose blocks
    fps_kernel<<<8 + 512, 256, 0, stream>>>(xyz, fps_i, nxyz, out0, feature, featT);
    // knn blocks 0..8191 + 2048 fused anchor-gather blocks
    knn_kernel<<<8192 + 2048, 256, 0, stream>>>(xyz, nxyz, knn, featT, fps_i, nfeat);
    prep_kernel<<<1024, 256, 0, stream>>>(featT, xyz, nxyz, nfeat, knn, dcache, stdpart_c);
    std_final_c<<<1, 64, 0, stream>>>(stdpart_c, invstd);
    mlp0c<<<B_ * S_, 256, 0, stream>>>(dcache, nfeat, invstd, alpha, beta, w_tr, b_tr,
                                       bnpart, tcache);
    bn_finalize<<<64, 256, 0, stream>>>(bnpart, g_tr, be_tr, bn_tr);
    mlp1c<<<B_ * S_, 256, 0, stream>>>(tcache, bn_tr, w1, b1, bnpart, ucache);
    bn_finalize<<<64, 256, 0, stream>>>(bnpart, g1, be1, bn_1);
    mlp2c<<<B_ * S_, 256, 0, stream>>>(tcache, ucache, bn_tr, bn_1, w2, b2, out1);
  } else {
    fps_kernel<<<8, 256, 0, stream>>>(xyz, fps_i, nxyz, out0, feature, featT);
    gather_nf<<<(B_ * S_ * D_) / 256, 256, 0, stream>>>(feature, fps_i, nfeat);
    knn_kernel<<<8192, 256, 0, stream>>>(xyz, nxyz, knn, nullptr, nullptr, nullptr);
    std_partial<<<B_ * 64, 256, 0, stream>>>(feature, xyz, nxyz, nfeat, knn, stdpart);
    std_final<<<1, 64, 0, stream>>>(stdpart, invstd);
    mlp_kernel<0><<<B_ * S_, 256, 0, stream>>>(feature, xyz, nxyz, nfeat, knn, invstd,
                                               alpha, beta, w_tr, b_tr, w1, b1, w2, b2,
                                               bn_tr, bn_1, bnpart, out1);
    bn_finalize<<<64, 256, 0, stream>>>(bnpart, g_tr, be_tr, bn_tr);
    mlp_kernel<1><<<B_ * S_, 256, 0, stream>>>(feature, xyz, nxyz, nfeat, knn, invstd,
                                               alpha, beta, w_tr, b_tr, w1, b1, w2, b2,
                                               bn_tr, bn_1, bnpart, out1);
    bn_finalize<<<64, 256, 0, stream>>>(bnpart, g1, be1, bn_1);
    mlp_kernel<2><<<B_ * S_, 256, 0, stream>>>(feature, xyz, nxyz, nfeat, knn, invstd,
                                               alpha, beta, w_tr, b_tr, w1, b1, w2, b2,
                                               bn_tr, bn_1, bnpart, out1);
  }
}